// Round 15
// baseline (146.888 us; speedup 1.0000x reference)
//
#include <hip/hip_runtime.h>
#include <hip/hip_bf16.h>
#include <math.h>

// SpikingNeuralNetwork: 3 chained bf16-MFMA GEMMs + elementwise epilogues.
// N = 2048. Round 15: 256x256-tile GEMM with counted-vmcnt deep pipeline.
// 8 waves (2x4) x (128x64) per wave, BK=64, 2-buffer LDS (128 KB), split-K=4
// -> grid 8x8x4 = 256 blocks = 1 block/CU. Per iteration: compute(cur) ->
// s_barrier -> stage tile t+2 into cur -> vmcnt(8) (waits tile t+1, issued a
// FULL iteration ago -> zero-stall steady state) -> s_barrier. Correct by
// construction: stage targets a buffer all waves finished reading (barrier 1);
// reads of next tile only after every wave's vmcnt confirms landing (barrier 2).
// Partials: 4x bf16 (accuracy proven in r8, absmax 0.0039). STDP rides comb2.

#define NN 2048
#define BK 64
#define KSL (NN / 4)        // 512 per K-split
#define KT (KSL / BK)       // 8 K-tiles per split
#define NT256 (NN / 256)    // 8 tiles per dim

typedef __attribute__((ext_vector_type(8))) short bf16x8;
typedef __attribute__((ext_vector_type(4))) float f32x4;
typedef __attribute__((ext_vector_type(4))) short s16x4;

#define SBAR()   asm volatile("s_barrier" ::: "memory")
#define VMCNT(n) asm volatile("s_waitcnt vmcnt(" #n ")" ::: "memory")

__device__ __forceinline__ short f2bf(float f) {
    union { float f; unsigned u; } a; a.f = f;
    unsigned r = a.u + 0x7FFFu + ((a.u >> 16) & 1u);   // RNE
    return (short)(r >> 16);
}

__device__ __forceinline__ float bf2f(short s) {
    union { unsigned u; float f; } a;
    a.u = ((unsigned)(unsigned short)s) << 16;
    return a.f;
}

__device__ __forceinline__ void gload16(const short* g, short* l) {
    __builtin_amdgcn_global_load_lds(
        (const __attribute__((address_space(1))) unsigned int*)g,
        (__attribute__((address_space(3))) unsigned int*)l, 16, 0, 0);
}

__device__ __forceinline__ float sigmoidf_(float x) {
    return 1.0f / (1.0f + expf(-x));
}

__device__ __forceinline__ void conv_item(const float* __restrict__ src,
                                          short* __restrict__ dst, int i) {
    float4 v = reinterpret_cast<const float4*>(src)[i];
    s16x4 o;
    o.x = f2bf(v.x); o.y = f2bf(v.y); o.z = f2bf(v.z); o.w = f2bf(v.w);
    reinterpret_cast<s16x4*>(dst)[i] = o;
}

// ---------------- conv x, W1 (+ zero flags) ----------------
__global__ void conv2_kernel(const float* __restrict__ s0, const float* __restrict__ s1,
                             short* __restrict__ d0, short* __restrict__ d1,
                             int* __restrict__ flags)
{
    int i = blockIdx.x * blockDim.x + threadIdx.x;   // over NN*NN/4
    if (blockIdx.y == 0) {
        conv_item(s0, d0, i);
        if (blockIdx.x < NN / 256)
            flags[blockIdx.x * blockDim.x + threadIdx.x] = 0;
    } else {
        conv_item(s1, d1, i);
    }
}

// ---------------- 256x256 deep-pipeline split-K=4 GEMM partial ----------------
// C_z = A[:, z*512 +: 512] @ B^T slice. P_z = bf16 partial at P + z*NSQ.
__global__ __launch_bounds__(512, 2) void gemm256(
    const short* __restrict__ A, const short* __restrict__ B,
    short* __restrict__ P)
{
    __shared__ short As[2][256 * BK] __attribute__((aligned(16)));   // 2 x 32 KB
    __shared__ short Bs[2][256 * BK] __attribute__((aligned(16)));   // 2 x 32 KB

    const int tid  = threadIdx.x;
    const int lane = tid & 63;
    const int wid  = tid >> 6;            // 0..7
    const int row0 = blockIdx.y * 256;
    const int col0 = blockIdx.x * 256;
    const int kbase = blockIdx.z * KSL;
    const int wm   = (wid >> 2) * 128;    // wave rows: 128 of 256
    const int wn   = (wid & 3) * 64;      // wave cols: 64 of 256
    const int lrow = lane & 15;
    const int lk16 = (lane >> 4) << 3;    // 0/8/16/24

    f32x4 acc[8][4] = {};                 // 128 VGPR accumulator

    // Stage one K-tile (256x64 A + 256x64 B) into buffer `buf`: 8 gload16
    // per thread. LDS dest linear (global_load_lds requirement); global
    // source inverse-swizzled so swizzled ds_reads return linear fragments.
    auto stage = [&](int buf, int k0) {
#pragma unroll
        for (int s = 0; s < 4; ++s) {
            int c = tid + s * 512;                       // chunk 0..2047
            int r = c >> 3;                              // row (8 chunks/row)
            int ksrc = ((c & 7) ^ (r & 7)) << 3;         // swizzled k
            gload16(A + (size_t)(row0 + r) * NN + k0 + ksrc, &As[buf][c * 8]);
            gload16(B + (size_t)(col0 + r) * NN + k0 + ksrc, &Bs[buf][c * 8]);
        }
    };

    // 64 MFMA per iteration per wave: B frags held across the iteration,
    // A frags loaded per 2-M-frag quad (keeps live set ~196 VGPR).
    auto compute = [&](int buf) {
        bf16x8 bf[4][2];
#pragma unroll
        for (int j = 0; j < 4; ++j) {
            const int row = wn + j * 16 + lrow;
#pragma unroll
            for (int kk = 0; kk < 2; ++kk) {
                const int ke = (lk16 + kk * 32) ^ ((row & 7) << 3);
                bf[j][kk] = *reinterpret_cast<const bf16x8*>(&Bs[buf][row * BK + ke]);
            }
        }
#pragma unroll
        for (int iq = 0; iq < 4; ++iq) {
            bf16x8 af[2][2];
#pragma unroll
            for (int ii = 0; ii < 2; ++ii) {
                const int row = wm + (iq * 2 + ii) * 16 + lrow;
#pragma unroll
                for (int kk = 0; kk < 2; ++kk) {
                    const int ke = (lk16 + kk * 32) ^ ((row & 7) << 3);
                    af[ii][kk] = *reinterpret_cast<const bf16x8*>(&As[buf][row * BK + ke]);
                }
            }
#pragma unroll
            for (int kk = 0; kk < 2; ++kk)
#pragma unroll
                for (int ii = 0; ii < 2; ++ii)
#pragma unroll
                    for (int j = 0; j < 4; ++j)
                        acc[iq * 2 + ii][j] = __builtin_amdgcn_mfma_f32_16x16x32_bf16(
                            af[ii][kk], bf[j][kk], acc[iq * 2 + ii][j], 0, 0, 0);
        }
    };

    // Prologue: tiles 0,1 in flight; wait tile 0 (8 of 16 outstanding).
    stage(0, kbase);
    stage(1, kbase + BK);
    VMCNT(8);
    SBAR();

    // Main loop: loads consumed at t were issued at t-1 (a full iteration of
    // MFMA ago) -> vmcnt(8) is satisfied without stalling in steady state.
#pragma unroll 1
    for (int t = 0; t < KT - 2; ++t) {
        compute(t & 1);
        SBAR();                              // all waves done reading buf t&1
        stage(t & 1, kbase + (t + 2) * BK);  // overwrite with tile t+2
        VMCNT(8);                            // tile t+1's 8 loads landed
        SBAR();
    }
    compute((KT - 2) & 1);
    VMCNT(0);                                // tile KT-1 landed (all waves)
    SBAR();
    compute((KT - 1) & 1);

    // bf16 partial write — C/D layout: col = lane&15, row = (lane>>4)*4 + reg
    short* outp = P + (size_t)blockIdx.z * NN * NN;
#pragma unroll
    for (int i = 0; i < 8; ++i) {
#pragma unroll
        for (int j = 0; j < 4; ++j) {
            const int gcol = col0 + wn + j * 16 + lrow;
#pragma unroll
            for (int r = 0; r < 4; ++r) {
                const int grow = row0 + wm + i * 16 + ((lane >> 4) << 2) + r;
                outp[(size_t)grow * NN + gcol] = f2bf(acc[i][j][r]);
            }
        }
    }
}

// ---------------- combine1 (4 partials -> v/HH/spike) + merged conv(W2) ----------------
__global__ void comb1_mix(
    const short* __restrict__ p0, const short* __restrict__ p1,
    const short* __restrict__ p2, const short* __restrict__ p3,
    const float* __restrict__ bias,
    const float* __restrict__ mp,
    const float* __restrict__ n_in, const float* __restrict__ m_in,
    const float* __restrict__ h_in,
    short* __restrict__ out_v,
    float* __restrict__ out_n, float* __restrict__ out_m,
    float* __restrict__ out_h,
    int* __restrict__ flags,
    const float* __restrict__ convsrc, short* __restrict__ convdst)
{
    int idx = blockIdx.x * blockDim.x + threadIdx.x;   // over NN*NN/4
    if (blockIdx.y == 1) { conv_item(convsrc, convdst, idx); return; }
    int row = idx >> 9;
    int g   = idx & 511;
    s16x4 a = reinterpret_cast<const s16x4*>(p0)[idx];
    s16x4 b = reinterpret_cast<const s16x4*>(p1)[idx];
    s16x4 c = reinterpret_cast<const s16x4*>(p2)[idx];
    s16x4 d = reinterpret_cast<const s16x4*>(p3)[idx];
    float4 bi = reinterpret_cast<const float4*>(bias)[g];
    float pre[4] = { bf2f(a.x) + bf2f(b.x) + bf2f(c.x) + bf2f(d.x) + bi.x,
                     bf2f(a.y) + bf2f(b.y) + bf2f(c.y) + bf2f(d.y) + bi.y,
                     bf2f(a.z) + bf2f(b.z) + bf2f(c.z) + bf2f(d.z) + bi.z,
                     bf2f(a.w) + bf2f(b.w) + bf2f(c.w) + bf2f(d.w) + bi.w };
    float4 mp4 = reinterpret_cast<const float4*>(mp)[g];
    float4 n4  = reinterpret_cast<const float4*>(n_in)[g];
    float4 m4  = reinterpret_cast<const float4*>(m_in)[g];
    float4 h4  = reinterpret_cast<const float4*>(h_in)[g];
    float mpv[4] = {mp4.x, mp4.y, mp4.z, mp4.w};
    float nv[4]  = {n4.x, n4.y, n4.z, n4.w};
    float mv[4]  = {m4.x, m4.y, m4.z, m4.w};
    float hv[4]  = {h4.x, h4.y, h4.z, h4.w};
    s16x4 vb;
    float on[4], om[4], oh[4];
#pragma unroll
    for (int t = 0; t < 4; ++t) {
        float v = 0.5f * mpv[t] + sigmoidf_(pre[t]);
        if (v > 1.0f) { flags[row] = 1; v = 0.0f; }
        vb[t] = f2bf(v);
        float an = 0.01f * (v + 55.0f) / (1.0f - expf(-(v + 55.0f) / 10.0f));
        float bn = 0.125f * expf(-(v + 65.0f) / 80.0f);
        float am = 0.1f  * (v + 40.0f) / (1.0f - expf(-(v + 40.0f) / 10.0f));
        float bm = 4.0f  * expf(-(v + 65.0f) / 18.0f);
        float ah = 0.07f * expf(-(v + 65.0f) / 20.0f);
        float bh = 1.0f  / (1.0f + expf(-(v + 35.0f) / 10.0f));
        on[t] = nv[t] + 0.01f * (an * (1.0f - nv[t]) - bn * nv[t]);
        om[t] = mv[t] + 0.01f * (am * (1.0f - mv[t]) - bm * mv[t]);
        oh[t] = hv[t] + 0.01f * (ah * (1.0f - hv[t]) - bh * hv[t]);
    }
    reinterpret_cast<s16x4*>(out_v)[idx] = vb;
    reinterpret_cast<float4*>(out_n)[idx] = make_float4(on[0], on[1], on[2], on[3]);
    reinterpret_cast<float4*>(out_m)[idx] = make_float4(om[0], om[1], om[2], om[3]);
    reinterpret_cast<float4*>(out_h)[idx] = make_float4(oh[0], oh[1], oh[2], oh[3]);
}

// -------- combine2 (4 partials -> bf16 sigmoid) + conv(W3) + STDP --------
__global__ void comb2_mix(
    const short* __restrict__ p0, const short* __restrict__ p1,
    const short* __restrict__ p2, const short* __restrict__ p3,
    const float* __restrict__ bias,
    short* __restrict__ out_bf,
    const float* __restrict__ convsrc, short* __restrict__ convdst,
    const float* __restrict__ w, const float* __restrict__ lst,
    const int* __restrict__ flags, float* __restrict__ outw)
{
    int idx = blockIdx.x * blockDim.x + threadIdx.x;   // over NN*NN/4
    if (blockIdx.y == 1) { conv_item(convsrc, convdst, idx); return; }
    if (blockIdx.y == 2) {
        // STDP weight update (flags finalized by combine1)
        int i  = idx >> 9;
        int j4 = (idx & 511) << 2;
        float4 wv = reinterpret_cast<const float4*>(w)[idx];
        float o[4] = {wv.x, wv.y, wv.z, wv.w};
        const int   rsi = flags[i];
        const float tsi = 10.0f - lst[i];
#pragma unroll
        for (int t = 0; t < 4; ++t) {
            int j = j4 + t;
            if (rsi | flags[j]) {
                float dtm = tsi - (10.0f - lst[j]);
                float dw = (dtm > 0.0f) ? (-0.015f * expf(-fabsf(dtm) / 25.0f))
                                        : ( 0.02f  * expf(-fabsf(dtm) / 15.0f));
                o[t] += dw;
            }
            o[t] = fminf(1.0f, fmaxf(-1.0f, o[t]));
        }
        reinterpret_cast<float4*>(outw)[idx] = make_float4(o[0], o[1], o[2], o[3]);
        return;
    }
    int g = idx & 511;
    s16x4 a = reinterpret_cast<const s16x4*>(p0)[idx];
    s16x4 b = reinterpret_cast<const s16x4*>(p1)[idx];
    s16x4 c = reinterpret_cast<const s16x4*>(p2)[idx];
    s16x4 d = reinterpret_cast<const s16x4*>(p3)[idx];
    float4 bi = reinterpret_cast<const float4*>(bias)[g];
    s16x4 o;
    o.x = f2bf(sigmoidf_(bf2f(a.x) + bf2f(b.x) + bf2f(c.x) + bf2f(d.x) + bi.x));
    o.y = f2bf(sigmoidf_(bf2f(a.y) + bf2f(b.y) + bf2f(c.y) + bf2f(d.y) + bi.y));
    o.z = f2bf(sigmoidf_(bf2f(a.z) + bf2f(b.z) + bf2f(c.z) + bf2f(d.z) + bi.z));
    o.w = f2bf(sigmoidf_(bf2f(a.w) + bf2f(b.w) + bf2f(c.w) + bf2f(d.w) + bi.w));
    reinterpret_cast<s16x4*>(out_bf)[idx] = o;
}

// ---------------- combine3 (4 partials -> f32 sigmoid) ----------------
__global__ void combine3(
    const short* __restrict__ p0, const short* __restrict__ p1,
    const short* __restrict__ p2, const short* __restrict__ p3,
    const float* __restrict__ bias, float* __restrict__ out_f)
{
    int idx = blockIdx.x * blockDim.x + threadIdx.x;
    int g = idx & 511;
    s16x4 a = reinterpret_cast<const s16x4*>(p0)[idx];
    s16x4 b = reinterpret_cast<const s16x4*>(p1)[idx];
    s16x4 c = reinterpret_cast<const s16x4*>(p2)[idx];
    s16x4 d = reinterpret_cast<const s16x4*>(p3)[idx];
    float4 bi = reinterpret_cast<const float4*>(bias)[g];
    reinterpret_cast<float4*>(out_f)[idx] = make_float4(
        sigmoidf_(bf2f(a.x) + bf2f(b.x) + bf2f(c.x) + bf2f(d.x) + bi.x),
        sigmoidf_(bf2f(a.y) + bf2f(b.y) + bf2f(c.y) + bf2f(d.y) + bi.y),
        sigmoidf_(bf2f(a.z) + bf2f(b.z) + bf2f(c.z) + bf2f(d.z) + bi.z),
        sigmoidf_(bf2f(a.w) + bf2f(b.w) + bf2f(c.w) + bf2f(d.w) + bi.w));
}

extern "C" void kernel_launch(void* const* d_in, const int* in_sizes, int n_in,
                              void* d_out, int out_size, void* d_ws, size_t ws_size,
                              hipStream_t stream)
{
    const float* x   = (const float*)d_in[0];
    const float* W1  = (const float*)d_in[1];
    const float* b1  = (const float*)d_in[2];
    const float* W2  = (const float*)d_in[3];
    const float* b2  = (const float*)d_in[4];
    const float* W3  = (const float*)d_in[5];
    const float* b3  = (const float*)d_in[6];
    const float* wts = (const float*)d_in[7];
    const float* lst = (const float*)d_in[8];
    const float* mp  = (const float*)d_in[9];
    const float* nin = (const float*)d_in[10];
    const float* min_ = (const float*)d_in[11];
    const float* hin = (const float*)d_in[12];

    const size_t NSQ = (size_t)NN * NN;
    float* out    = (float*)d_out;          // [N,N] final MLP output
    float* out_w  = out + NSQ;              // new_weights
    float* out_n  = out + 2 * NSQ;
    float* out_m  = out + 3 * NSQ;
    float* out_h  = out + 4 * NSQ;

    // ws (48 MB + flags): R1 = xb->vb->h1b ; R2 = w1b->w2b->w3b ;
    // R3..R6 = 4 bf16 partials (P). All GEMMs: A=R1, B=R2, P=R3.
    short* R1 = (short*)d_ws;
    short* R2 = R1 + NSQ;
    short* P  = R2 + NSQ;           // 4 contiguous partials
    int* flags = (int*)(P + 4 * NSQ);

    const int convBlocks = (int)(NSQ / 4 / 256);   // 4096 per array

    dim3 ggrid(NT256, NT256, 4);    // 8x8x4 = 256 blocks (1/CU)

    // 1: x->R1, W1->R2 (+ zero flags)
    conv2_kernel<<<dim3(convBlocks, 2), 256, 0, stream>>>(x, W1, R1, R2, flags);
    // 2: GEMM1 partials: x @ W1^T -> P0..P3
    gemm256<<<ggrid, 512, 0, stream>>>(R1, R2, P);
    // 3: combine1 (v->R1, n/m/h, flags) + conv W2->R2
    comb1_mix<<<dim3(convBlocks, 2), 256, 0, stream>>>(
        P, P + NSQ, P + 2 * NSQ, P + 3 * NSQ, b1, mp, nin, min_, hin,
        R1, out_n, out_m, out_h, flags, W2, R2);
    // 4: GEMM2 partials: v @ W2^T -> P0..P3
    gemm256<<<ggrid, 512, 0, stream>>>(R1, R2, P);
    // 5: combine2 (h1->R1) + conv W3->R2 + STDP (y==2)
    comb2_mix<<<dim3(convBlocks, 3), 256, 0, stream>>>(
        P, P + NSQ, P + 2 * NSQ, P + 3 * NSQ, b2, R1, W3, R2,
        wts, lst, flags, out_w);
    // 6: GEMM3 partials: h1 @ W3^T -> P0..P3
    gemm256<<<ggrid, 512, 0, stream>>>(R1, R2, P);
    // 7: combine3: out = sigmoid(.) -> f32
    combine3<<<convBlocks, 256, 0, stream>>>(
        P, P + NSQ, P + 2 * NSQ, P + 3 * NSQ, b3, out);
}

// Round 16
// 123.606 us; speedup vs baseline: 1.1884x; 1.1884x over previous
//
#include <hip/hip_runtime.h>
#include <hip/hip_bf16.h>
#include <math.h>

// SpikingNeuralNetwork: 3 chained bf16-MFMA GEMMs + elementwise epilogues.
// N = 2048. Round 16: revert to the round-11 best (123.9 us) byte-identical.
// Config: split-K=2 GEMM partials (128x128 tile, BK=64 double-buffered LDS,
// 8 waves, 2 blocks/CU, XOR-swizzled staging), bf16 partials + combine
// kernels, conv-W2 merged into combine1's dispatch, conv-W3 into combine2's,
// STDP as the z==2 slice of GEMM2's dispatch. 7 launches.

#define NN 2048
#define BK 64
#define KHALF (NN / 2)
#define KTH (KHALF / BK)   // 16 K-tiles per half
#define NT (NN / 128)      // 16 tiles per dim

typedef __attribute__((ext_vector_type(8))) short bf16x8;
typedef __attribute__((ext_vector_type(4))) float f32x4;
typedef __attribute__((ext_vector_type(4))) short s16x4;

__device__ __forceinline__ short f2bf(float f) {
    union { float f; unsigned u; } a; a.f = f;
    unsigned r = a.u + 0x7FFFu + ((a.u >> 16) & 1u);   // RNE
    return (short)(r >> 16);
}

__device__ __forceinline__ float bf2f(short s) {
    union { unsigned u; float f; } a;
    a.u = ((unsigned)(unsigned short)s) << 16;
    return a.f;
}

__device__ __forceinline__ void gload16(const short* g, short* l) {
    __builtin_amdgcn_global_load_lds(
        (const __attribute__((address_space(1))) unsigned int*)g,
        (__attribute__((address_space(3))) unsigned int*)l, 16, 0, 0);
}

__device__ __forceinline__ float sigmoidf_(float x) {
    return 1.0f / (1.0f + expf(-x));
}

__device__ __forceinline__ void conv_item(const float* __restrict__ src,
                                          short* __restrict__ dst, int i) {
    float4 v = reinterpret_cast<const float4*>(src)[i];
    s16x4 o;
    o.x = f2bf(v.x); o.y = f2bf(v.y); o.z = f2bf(v.z); o.w = f2bf(v.w);
    reinterpret_cast<s16x4*>(dst)[i] = o;
}

// ---------------- conv x, W1 (+ zero flags) ----------------
__global__ void conv2_kernel(const float* __restrict__ s0, const float* __restrict__ s1,
                             short* __restrict__ d0, short* __restrict__ d1,
                             int* __restrict__ flags)
{
    int i = blockIdx.x * blockDim.x + threadIdx.x;   // over NN*NN/4
    if (blockIdx.y == 0) {
        conv_item(s0, d0, i);
        if (blockIdx.x < NN / 256)
            flags[blockIdx.x * blockDim.x + threadIdx.x] = 0;
    } else {
        conv_item(s1, d1, i);
    }
}

// ---------------- split-K=2 GEMM body (r7 config) ----------------
// C_z = A[:, z*1024 +: 1024] @ B^T slice. 128x128 tile, 8 waves (2x4) of
// 64x32, BK=64 double-buffered (64 KB LDS), XOR-swizzled. 2 blocks/CU.
__device__ __forceinline__ void gemm_body(
    const short* __restrict__ A, const short* __restrict__ B,
    short* __restrict__ P, short (*As)[128 * BK], short (*Bs)[128 * BK])
{
    const int tid  = threadIdx.x;
    const int lane = tid & 63;
    const int wid  = tid >> 6;          // 0..7
    const int row0 = blockIdx.y * 128;
    const int col0 = blockIdx.x * 128;
    const int kbase = blockIdx.z * KHALF;
    const int wm   = (wid >> 2) * 64;   // wave sub-tile origin in M (0/64)
    const int wn   = (wid & 3) * 32;    // in N (0/32/64/96)
    const int lrow = lane & 15;
    const int lk16 = (lane >> 4) << 3;  // 0/8/16/24

    f32x4 acc[4][2] = {};

    // LDS dest linear (global_load_lds requirement); global source inverse-
    // swizzled so a swizzled ds_read returns linear fragments (rule #21).
    auto stage = [&](int buf, int k0) {
#pragma unroll
        for (int s = 0; s < 2; ++s) {
            int c = tid + s * 512;                       // chunk id 0..1023
            int r = c >> 3;                              // row in tile
            int ksrc = ((c & 7) ^ (r & 7)) << 3;         // swizzled k (bf16 elems)
            gload16(A + (size_t)(row0 + r) * NN + k0 + ksrc, &As[buf][c * 8]);
            gload16(B + (size_t)(col0 + r) * NN + k0 + ksrc, &Bs[buf][c * 8]);
        }
    };

    auto compute = [&](int buf) {
        bf16x8 af[4][2], bfv[2][2];
#pragma unroll
        for (int i = 0; i < 4; ++i) {
            const int row = wm + i * 16 + lrow;
#pragma unroll
            for (int kk = 0; kk < 2; ++kk) {
                const int ke = (lk16 + kk * 32) ^ ((row & 7) << 3);
                af[i][kk] = *reinterpret_cast<const bf16x8*>(&As[buf][row * BK + ke]);
            }
        }
#pragma unroll
        for (int j = 0; j < 2; ++j) {
            const int row = wn + j * 16 + lrow;
#pragma unroll
            for (int kk = 0; kk < 2; ++kk) {
                const int ke = (lk16 + kk * 32) ^ ((row & 7) << 3);
                bfv[j][kk] = *reinterpret_cast<const bf16x8*>(&Bs[buf][row * BK + ke]);
            }
        }
#pragma unroll
        for (int kk = 0; kk < 2; ++kk)
#pragma unroll
            for (int i = 0; i < 4; ++i)
#pragma unroll
                for (int j = 0; j < 2; ++j)
                    acc[i][j] = __builtin_amdgcn_mfma_f32_16x16x32_bf16(
                        af[i][kk], bfv[j][kk], acc[i][j], 0, 0, 0);
    };

    // 2-phase pipeline: STAGE(next) before compute(cur); one vmcnt(0)+barrier
    // per iteration (__syncthreads). 2 blocks/CU fill each other's stalls.
    stage(0, kbase);
    __syncthreads();
    int cur = 0;
    for (int t = 0; t < KTH - 1; ++t) {
        stage(cur ^ 1, kbase + (t + 1) * BK);
        compute(cur);
        __syncthreads();
        cur ^= 1;
    }
    compute(cur);

    // write bf16 partial — C/D layout: col = lane&15, row = (lane>>4)*4 + reg
    short* outp = P + (size_t)blockIdx.z * NN * NN;
#pragma unroll
    for (int i = 0; i < 4; ++i) {
#pragma unroll
        for (int j = 0; j < 2; ++j) {
            const int gcol = col0 + wn + j * 16 + lrow;
#pragma unroll
            for (int r = 0; r < 4; ++r) {
                const int grow = row0 + wm + i * 16 + ((lane >> 4) << 2) + r;
                outp[(size_t)grow * NN + gcol] = f2bf(acc[i][j][r]);
            }
        }
    }
}

__global__ __launch_bounds__(512) void gemm_partial(
    const short* __restrict__ A, const short* __restrict__ B,
    short* __restrict__ P)
{
    __shared__ short As[2][128 * BK] __attribute__((aligned(16)));
    __shared__ short Bs[2][128 * BK] __attribute__((aligned(16)));
    gemm_body(A, B, P, As, Bs);
}

// GEMM2 + STDP fused dispatch: grid (16,16,3); z==2 blocks run STDP
// (overlaps the GEMM; STDP only needs flags, finalized by combine1).
__global__ __launch_bounds__(512) void gemm_stdp(
    const short* __restrict__ A, const short* __restrict__ B,
    short* __restrict__ P,
    const float* __restrict__ w, const float* __restrict__ lst,
    const int* __restrict__ flags, float* __restrict__ outw)
{
    __shared__ short As[2][128 * BK] __attribute__((aligned(16)));
    __shared__ short Bs[2][128 * BK] __attribute__((aligned(16)));
    if (blockIdx.z == 2) {
        const int bflat = blockIdx.y * gridDim.x + blockIdx.x;   // 0..255
#pragma unroll
        for (int u = 0; u < 8; ++u) {
            int idx = bflat * 4096 + u * 512 + threadIdx.x;      // over NN*NN/4
            int i  = idx >> 9;
            int j4 = (idx & 511) << 2;
            float4 wv = reinterpret_cast<const float4*>(w)[idx];
            float o[4] = {wv.x, wv.y, wv.z, wv.w};
            const int   rsi = flags[i];
            const float tsi = 10.0f - lst[i];
#pragma unroll
            for (int t = 0; t < 4; ++t) {
                int j = j4 + t;
                if (rsi | flags[j]) {
                    float dtm = tsi - (10.0f - lst[j]);
                    float dw = (dtm > 0.0f) ? (-0.015f * expf(-fabsf(dtm) / 25.0f))
                                            : ( 0.02f  * expf(-fabsf(dtm) / 15.0f));
                    o[t] += dw;
                }
                o[t] = fminf(1.0f, fmaxf(-1.0f, o[t]));
            }
            reinterpret_cast<float4*>(outw)[idx] = make_float4(o[0], o[1], o[2], o[3]);
        }
        return;
    }
    gemm_body(A, B, P, As, Bs);
}

// ---------------- combine1 (v/HH/spike) + merged conv(W2) ----------------
__global__ void comb1_mix(
    const short* __restrict__ p0, const short* __restrict__ p1,
    const float* __restrict__ bias,
    const float* __restrict__ mp,
    const float* __restrict__ n_in, const float* __restrict__ m_in,
    const float* __restrict__ h_in,
    short* __restrict__ out_v,
    float* __restrict__ out_n, float* __restrict__ out_m,
    float* __restrict__ out_h,
    int* __restrict__ flags,
    const float* __restrict__ convsrc, short* __restrict__ convdst)
{
    int idx = blockIdx.x * blockDim.x + threadIdx.x;   // over NN*NN/4
    if (blockIdx.y == 1) { conv_item(convsrc, convdst, idx); return; }
    int row = idx >> 9;
    int g   = idx & 511;
    s16x4 a = reinterpret_cast<const s16x4*>(p0)[idx];
    s16x4 b = reinterpret_cast<const s16x4*>(p1)[idx];
    float4 bi = reinterpret_cast<const float4*>(bias)[g];
    float pre[4] = { bf2f(a.x) + bf2f(b.x) + bi.x,
                     bf2f(a.y) + bf2f(b.y) + bi.y,
                     bf2f(a.z) + bf2f(b.z) + bi.z,
                     bf2f(a.w) + bf2f(b.w) + bi.w };
    float4 mp4 = reinterpret_cast<const float4*>(mp)[g];
    float4 n4  = reinterpret_cast<const float4*>(n_in)[g];
    float4 m4  = reinterpret_cast<const float4*>(m_in)[g];
    float4 h4  = reinterpret_cast<const float4*>(h_in)[g];
    float mpv[4] = {mp4.x, mp4.y, mp4.z, mp4.w};
    float nv[4]  = {n4.x, n4.y, n4.z, n4.w};
    float mv[4]  = {m4.x, m4.y, m4.z, m4.w};
    float hv[4]  = {h4.x, h4.y, h4.z, h4.w};
    s16x4 vb;
    float on[4], om[4], oh[4];
#pragma unroll
    for (int t = 0; t < 4; ++t) {
        float v = 0.5f * mpv[t] + sigmoidf_(pre[t]);
        if (v > 1.0f) { flags[row] = 1; v = 0.0f; }
        vb[t] = f2bf(v);
        float an = 0.01f * (v + 55.0f) / (1.0f - expf(-(v + 55.0f) / 10.0f));
        float bn = 0.125f * expf(-(v + 65.0f) / 80.0f);
        float am = 0.1f  * (v + 40.0f) / (1.0f - expf(-(v + 40.0f) / 10.0f));
        float bm = 4.0f  * expf(-(v + 65.0f) / 18.0f);
        float ah = 0.07f * expf(-(v + 65.0f) / 20.0f);
        float bh = 1.0f  / (1.0f + expf(-(v + 35.0f) / 10.0f));
        on[t] = nv[t] + 0.01f * (an * (1.0f - nv[t]) - bn * nv[t]);
        om[t] = mv[t] + 0.01f * (am * (1.0f - mv[t]) - bm * mv[t]);
        oh[t] = hv[t] + 0.01f * (ah * (1.0f - hv[t]) - bh * hv[t]);
    }
    reinterpret_cast<s16x4*>(out_v)[idx] = vb;
    reinterpret_cast<float4*>(out_n)[idx] = make_float4(on[0], on[1], on[2], on[3]);
    reinterpret_cast<float4*>(out_m)[idx] = make_float4(om[0], om[1], om[2], om[3]);
    reinterpret_cast<float4*>(out_h)[idx] = make_float4(oh[0], oh[1], oh[2], oh[3]);
}

// ---------------- combine2 (bf16 sigmoid) + merged conv(W3) ----------------
__global__ void comb2_mix(
    const short* __restrict__ p0, const short* __restrict__ p1,
    const float* __restrict__ bias,
    short* __restrict__ out_bf,
    const float* __restrict__ convsrc, short* __restrict__ convdst)
{
    int idx = blockIdx.x * blockDim.x + threadIdx.x;
    if (blockIdx.y == 1) { conv_item(convsrc, convdst, idx); return; }
    int g = idx & 511;
    s16x4 a = reinterpret_cast<const s16x4*>(p0)[idx];
    s16x4 b = reinterpret_cast<const s16x4*>(p1)[idx];
    float4 bi = reinterpret_cast<const float4*>(bias)[g];
    s16x4 o;
    o.x = f2bf(sigmoidf_(bf2f(a.x) + bf2f(b.x) + bi.x));
    o.y = f2bf(sigmoidf_(bf2f(a.y) + bf2f(b.y) + bi.y));
    o.z = f2bf(sigmoidf_(bf2f(a.z) + bf2f(b.z) + bi.z));
    o.w = f2bf(sigmoidf_(bf2f(a.w) + bf2f(b.w) + bi.w));
    reinterpret_cast<s16x4*>(out_bf)[idx] = o;
}

// ---------------- combine3 (f32 sigmoid) ----------------
__global__ void combine3(
    const short* __restrict__ p0, const short* __restrict__ p1,
    const float* __restrict__ bias, float* __restrict__ out_f)
{
    int idx = blockIdx.x * blockDim.x + threadIdx.x;
    int g = idx & 511;
    s16x4 a = reinterpret_cast<const s16x4*>(p0)[idx];
    s16x4 b = reinterpret_cast<const s16x4*>(p1)[idx];
    float4 bi = reinterpret_cast<const float4*>(bias)[g];
    reinterpret_cast<float4*>(out_f)[idx] = make_float4(
        sigmoidf_(bf2f(a.x) + bf2f(b.x) + bi.x),
        sigmoidf_(bf2f(a.y) + bf2f(b.y) + bi.y),
        sigmoidf_(bf2f(a.z) + bf2f(b.z) + bi.z),
        sigmoidf_(bf2f(a.w) + bf2f(b.w) + bi.w));
}

extern "C" void kernel_launch(void* const* d_in, const int* in_sizes, int n_in,
                              void* d_out, int out_size, void* d_ws, size_t ws_size,
                              hipStream_t stream)
{
    const float* x   = (const float*)d_in[0];
    const float* W1  = (const float*)d_in[1];
    const float* b1  = (const float*)d_in[2];
    const float* W2  = (const float*)d_in[3];
    const float* b2  = (const float*)d_in[4];
    const float* W3  = (const float*)d_in[5];
    const float* b3  = (const float*)d_in[6];
    const float* wts = (const float*)d_in[7];
    const float* lst = (const float*)d_in[8];
    const float* mp  = (const float*)d_in[9];
    const float* nin = (const float*)d_in[10];
    const float* min_ = (const float*)d_in[11];
    const float* hin = (const float*)d_in[12];

    const size_t NSQ = (size_t)NN * NN;
    float* out    = (float*)d_out;          // [N,N] final MLP output
    float* out_w  = out + NSQ;              // new_weights
    float* out_n  = out + 2 * NSQ;
    float* out_m  = out + 3 * NSQ;
    float* out_h  = out + 4 * NSQ;

    // ws layout (48 MB + flags): R1 xb->w3b; R2 w1b->h1b; R3 vb; R4 w2b;
    // P = 2x8MB bf16 partials.
    short* R1 = (short*)d_ws;
    short* R2 = R1 + NSQ;
    short* R3 = R2 + NSQ;
    short* R4 = R3 + NSQ;
    short* P  = R4 + NSQ;
    int* flags = (int*)(P + 2 * NSQ);

    const int convBlocks = (int)(NSQ / 4 / 256);   // 4096 per array

    // 1: x->R1, W1->R2 (+ zero flags)
    conv2_kernel<<<dim3(convBlocks, 2), 256, 0, stream>>>(x, W1, R1, R2, flags);
    // 2: GEMM1 partials: x @ W1^T
    gemm_partial<<<dim3(NT, NT, 2), 512, 0, stream>>>(R1, R2, P);
    // 3: combine1 (v->R3, n/m/h, flags) + conv W2->R4
    comb1_mix<<<dim3(convBlocks, 2), 256, 0, stream>>>(
        P, P + NSQ, b1, mp, nin, min_, hin,
        R3, out_n, out_m, out_h, flags, W2, R4);
    // 4: GEMM2 partials (v @ W2^T) + STDP overlapped as z==2 slice
    gemm_stdp<<<dim3(NT, NT, 3), 512, 0, stream>>>(R3, R4, P, wts, lst, flags, out_w);
    // 5: combine2 (h1->R2) + conv W3->R1
    comb2_mix<<<dim3(convBlocks, 2), 256, 0, stream>>>(
        P, P + NSQ, b2, R2, W3, R1);
    // 6: GEMM3 partials: h1 @ W3^T
    gemm_partial<<<dim3(NT, NT, 2), 512, 0, stream>>>(R2, R1, P);
    // 7: combine3: out = sigmoid(.) -> f32
    combine3<<<convBlocks, 256, 0, stream>>>(P, P + NSQ, b3, out);
}

// Round 17
// 122.916 us; speedup vs baseline: 1.1950x; 1.0056x over previous
//
#include <hip/hip_runtime.h>
#include <hip/hip_bf16.h>
#include <math.h>

// SpikingNeuralNetwork: 3 chained bf16-MFMA GEMMs + elementwise epilogues.
// N = 2048. Round 17: r16 base (123.6 us) + XCD-locality block remap for the
// GEMM dispatches. 1D grid; bid&7 = XCD (round-robin assumption, perf-only);
// each XCD gets 4 row-panels x 16 cols x 1 K-half -> per-XCD operand
// footprint 5 MB with 320 KB per-k-iter window (L2-resident), cutting
// L3 re-fetch of staging traffic ~2x. GEMM body/combines byte-identical.

#define NN 2048
#define BK 64
#define KHALF (NN / 2)
#define KTH (KHALF / BK)   // 16 K-tiles per half
#define NT (NN / 128)      // 16 tiles per dim

typedef __attribute__((ext_vector_type(8))) short bf16x8;
typedef __attribute__((ext_vector_type(4))) float f32x4;
typedef __attribute__((ext_vector_type(4))) short s16x4;

__device__ __forceinline__ short f2bf(float f) {
    union { float f; unsigned u; } a; a.f = f;
    unsigned r = a.u + 0x7FFFu + ((a.u >> 16) & 1u);   // RNE
    return (short)(r >> 16);
}

__device__ __forceinline__ float bf2f(short s) {
    union { unsigned u; float f; } a;
    a.u = ((unsigned)(unsigned short)s) << 16;
    return a.f;
}

__device__ __forceinline__ void gload16(const short* g, short* l) {
    __builtin_amdgcn_global_load_lds(
        (const __attribute__((address_space(1))) unsigned int*)g,
        (__attribute__((address_space(3))) unsigned int*)l, 16, 0, 0);
}

__device__ __forceinline__ float sigmoidf_(float x) {
    return 1.0f / (1.0f + expf(-x));
}

__device__ __forceinline__ void conv_item(const float* __restrict__ src,
                                          short* __restrict__ dst, int i) {
    float4 v = reinterpret_cast<const float4*>(src)[i];
    s16x4 o;
    o.x = f2bf(v.x); o.y = f2bf(v.y); o.z = f2bf(v.z); o.w = f2bf(v.w);
    reinterpret_cast<s16x4*>(dst)[i] = o;
}

// ---------------- conv x, W1 (+ zero flags) ----------------
__global__ void conv2_kernel(const float* __restrict__ s0, const float* __restrict__ s1,
                             short* __restrict__ d0, short* __restrict__ d1,
                             int* __restrict__ flags)
{
    int i = blockIdx.x * blockDim.x + threadIdx.x;   // over NN*NN/4
    if (blockIdx.y == 0) {
        conv_item(s0, d0, i);
        if (blockIdx.x < NN / 256)
            flags[blockIdx.x * blockDim.x + threadIdx.x] = 0;
    } else {
        conv_item(s1, d1, i);
    }
}

// ---------------- split-K=2 GEMM body (r7 config) ----------------
// C_z = A[:, z*1024 +: 1024] @ B^T slice. 128x128 tile, 8 waves (2x4) of
// 64x32, BK=64 double-buffered (64 KB LDS), XOR-swizzled. 2 blocks/CU.
// (row0, col0, z supplied by the XCD-locality decode in the wrappers.)
__device__ __forceinline__ void gemm_body(
    const short* __restrict__ A, const short* __restrict__ B,
    short* __restrict__ P, short (*As)[128 * BK], short (*Bs)[128 * BK],
    const int row0, const int col0, const int z)
{
    const int tid  = threadIdx.x;
    const int lane = tid & 63;
    const int wid  = tid >> 6;          // 0..7
    const int kbase = z * KHALF;
    const int wm   = (wid >> 2) * 64;   // wave sub-tile origin in M (0/64)
    const int wn   = (wid & 3) * 32;    // in N (0/32/64/96)
    const int lrow = lane & 15;
    const int lk16 = (lane >> 4) << 3;  // 0/8/16/24

    f32x4 acc[4][2] = {};

    // LDS dest linear (global_load_lds requirement); global source inverse-
    // swizzled so a swizzled ds_read returns linear fragments (rule #21).
    auto stage = [&](int buf, int k0) {
#pragma unroll
        for (int s = 0; s < 2; ++s) {
            int c = tid + s * 512;                       // chunk id 0..1023
            int r = c >> 3;                              // row in tile
            int ksrc = ((c & 7) ^ (r & 7)) << 3;         // swizzled k (bf16 elems)
            gload16(A + (size_t)(row0 + r) * NN + k0 + ksrc, &As[buf][c * 8]);
            gload16(B + (size_t)(col0 + r) * NN + k0 + ksrc, &Bs[buf][c * 8]);
        }
    };

    auto compute = [&](int buf) {
        bf16x8 af[4][2], bfv[2][2];
#pragma unroll
        for (int i = 0; i < 4; ++i) {
            const int row = wm + i * 16 + lrow;
#pragma unroll
            for (int kk = 0; kk < 2; ++kk) {
                const int ke = (lk16 + kk * 32) ^ ((row & 7) << 3);
                af[i][kk] = *reinterpret_cast<const bf16x8*>(&As[buf][row * BK + ke]);
            }
        }
#pragma unroll
        for (int j = 0; j < 2; ++j) {
            const int row = wn + j * 16 + lrow;
#pragma unroll
            for (int kk = 0; kk < 2; ++kk) {
                const int ke = (lk16 + kk * 32) ^ ((row & 7) << 3);
                bfv[j][kk] = *reinterpret_cast<const bf16x8*>(&Bs[buf][row * BK + ke]);
            }
        }
#pragma unroll
        for (int kk = 0; kk < 2; ++kk)
#pragma unroll
            for (int i = 0; i < 4; ++i)
#pragma unroll
                for (int j = 0; j < 2; ++j)
                    acc[i][j] = __builtin_amdgcn_mfma_f32_16x16x32_bf16(
                        af[i][kk], bfv[j][kk], acc[i][j], 0, 0, 0);
    };

    // 2-phase pipeline: STAGE(next) before compute(cur); one vmcnt(0)+barrier
    // per iteration (__syncthreads). 2 blocks/CU fill each other's stalls.
    stage(0, kbase);
    __syncthreads();
    int cur = 0;
    for (int t = 0; t < KTH - 1; ++t) {
        stage(cur ^ 1, kbase + (t + 1) * BK);
        compute(cur);
        __syncthreads();
        cur ^= 1;
    }
    compute(cur);

    // write bf16 partial — C/D layout: col = lane&15, row = (lane>>4)*4 + reg
    short* outp = P + (size_t)z * NN * NN;
#pragma unroll
    for (int i = 0; i < 4; ++i) {
#pragma unroll
        for (int j = 0; j < 2; ++j) {
            const int gcol = col0 + wn + j * 16 + lrow;
#pragma unroll
            for (int r = 0; r < 4; ++r) {
                const int grow = row0 + wm + i * 16 + ((lane >> 4) << 2) + r;
                outp[(size_t)grow * NN + gcol] = f2bf(acc[i][j][r]);
            }
        }
    }
}

// XCD-locality decode: bid&7 = XCD (HW round-robin assumption, perf-only).
// XCD p -> z = p>>2, rows (p&3)*4 .. +3; slot = bid>>3 -> row-in-group =
// slot&3, col = slot>>2. Bijective over 512 blocks = 16r x 16c x 2z.
__device__ __forceinline__ void xcd_decode(int bid, int& row0, int& col0, int& z)
{
    const int xcd  = bid & 7;
    const int slot = bid >> 3;          // 0..63
    z    = xcd >> 2;
    row0 = ((xcd & 3) * 4 + (slot & 3)) * 128;
    col0 = (slot >> 2) * 128;
}

__global__ __launch_bounds__(512) void gemm_partial(
    const short* __restrict__ A, const short* __restrict__ B,
    short* __restrict__ P)
{
    __shared__ short As[2][128 * BK] __attribute__((aligned(16)));
    __shared__ short Bs[2][128 * BK] __attribute__((aligned(16)));
    int row0, col0, z;
    xcd_decode(blockIdx.x, row0, col0, z);
    gemm_body(A, B, P, As, Bs, row0, col0, z);
}

// GEMM2 + STDP fused dispatch: 768 blocks 1D; bid >= 512 runs STDP
// (overlaps the GEMM; STDP only needs flags, finalized by combine1).
__global__ __launch_bounds__(512) void gemm_stdp(
    const short* __restrict__ A, const short* __restrict__ B,
    short* __restrict__ P,
    const float* __restrict__ w, const float* __restrict__ lst,
    const int* __restrict__ flags, float* __restrict__ outw)
{
    __shared__ short As[2][128 * BK] __attribute__((aligned(16)));
    __shared__ short Bs[2][128 * BK] __attribute__((aligned(16)));
    if (blockIdx.x >= 512) {
        const int bflat = blockIdx.x - 512;              // 0..255
#pragma unroll
        for (int u = 0; u < 8; ++u) {
            int idx = bflat * 4096 + u * 512 + threadIdx.x;  // over NN*NN/4
            int i  = idx >> 9;
            int j4 = (idx & 511) << 2;
            float4 wv = reinterpret_cast<const float4*>(w)[idx];
            float o[4] = {wv.x, wv.y, wv.z, wv.w};
            const int   rsi = flags[i];
            const float tsi = 10.0f - lst[i];
#pragma unroll
            for (int t = 0; t < 4; ++t) {
                int j = j4 + t;
                if (rsi | flags[j]) {
                    float dtm = tsi - (10.0f - lst[j]);
                    float dw = (dtm > 0.0f) ? (-0.015f * expf(-fabsf(dtm) / 25.0f))
                                            : ( 0.02f  * expf(-fabsf(dtm) / 15.0f));
                    o[t] += dw;
                }
                o[t] = fminf(1.0f, fmaxf(-1.0f, o[t]));
            }
            reinterpret_cast<float4*>(outw)[idx] = make_float4(o[0], o[1], o[2], o[3]);
        }
        return;
    }
    int row0, col0, z;
    xcd_decode(blockIdx.x, row0, col0, z);
    gemm_body(A, B, P, As, Bs, row0, col0, z);
}

// ---------------- combine1 (v/HH/spike) + merged conv(W2) ----------------
__global__ void comb1_mix(
    const short* __restrict__ p0, const short* __restrict__ p1,
    const float* __restrict__ bias,
    const float* __restrict__ mp,
    const float* __restrict__ n_in, const float* __restrict__ m_in,
    const float* __restrict__ h_in,
    short* __restrict__ out_v,
    float* __restrict__ out_n, float* __restrict__ out_m,
    float* __restrict__ out_h,
    int* __restrict__ flags,
    const float* __restrict__ convsrc, short* __restrict__ convdst)
{
    int idx = blockIdx.x * blockDim.x + threadIdx.x;   // over NN*NN/4
    if (blockIdx.y == 1) { conv_item(convsrc, convdst, idx); return; }
    int row = idx >> 9;
    int g   = idx & 511;
    s16x4 a = reinterpret_cast<const s16x4*>(p0)[idx];
    s16x4 b = reinterpret_cast<const s16x4*>(p1)[idx];
    float4 bi = reinterpret_cast<const float4*>(bias)[g];
    float pre[4] = { bf2f(a.x) + bf2f(b.x) + bi.x,
                     bf2f(a.y) + bf2f(b.y) + bi.y,
                     bf2f(a.z) + bf2f(b.z) + bi.z,
                     bf2f(a.w) + bf2f(b.w) + bi.w };
    float4 mp4 = reinterpret_cast<const float4*>(mp)[g];
    float4 n4  = reinterpret_cast<const float4*>(n_in)[g];
    float4 m4  = reinterpret_cast<const float4*>(m_in)[g];
    float4 h4  = reinterpret_cast<const float4*>(h_in)[g];
    float mpv[4] = {mp4.x, mp4.y, mp4.z, mp4.w};
    float nv[4]  = {n4.x, n4.y, n4.z, n4.w};
    float mv[4]  = {m4.x, m4.y, m4.z, m4.w};
    float hv[4]  = {h4.x, h4.y, h4.z, h4.w};
    s16x4 vb;
    float on[4], om[4], oh[4];
#pragma unroll
    for (int t = 0; t < 4; ++t) {
        float v = 0.5f * mpv[t] + sigmoidf_(pre[t]);
        if (v > 1.0f) { flags[row] = 1; v = 0.0f; }
        vb[t] = f2bf(v);
        float an = 0.01f * (v + 55.0f) / (1.0f - expf(-(v + 55.0f) / 10.0f));
        float bn = 0.125f * expf(-(v + 65.0f) / 80.0f);
        float am = 0.1f  * (v + 40.0f) / (1.0f - expf(-(v + 40.0f) / 10.0f));
        float bm = 4.0f  * expf(-(v + 65.0f) / 18.0f);
        float ah = 0.07f * expf(-(v + 65.0f) / 20.0f);
        float bh = 1.0f  / (1.0f + expf(-(v + 35.0f) / 10.0f));
        on[t] = nv[t] + 0.01f * (an * (1.0f - nv[t]) - bn * nv[t]);
        om[t] = mv[t] + 0.01f * (am * (1.0f - mv[t]) - bm * mv[t]);
        oh[t] = hv[t] + 0.01f * (ah * (1.0f - hv[t]) - bh * hv[t]);
    }
    reinterpret_cast<s16x4*>(out_v)[idx] = vb;
    reinterpret_cast<float4*>(out_n)[idx] = make_float4(on[0], on[1], on[2], on[3]);
    reinterpret_cast<float4*>(out_m)[idx] = make_float4(om[0], om[1], om[2], om[3]);
    reinterpret_cast<float4*>(out_h)[idx] = make_float4(oh[0], oh[1], oh[2], oh[3]);
}

// ---------------- combine2 (bf16 sigmoid) + merged conv(W3) ----------------
__global__ void comb2_mix(
    const short* __restrict__ p0, const short* __restrict__ p1,
    const float* __restrict__ bias,
    short* __restrict__ out_bf,
    const float* __restrict__ convsrc, short* __restrict__ convdst)
{
    int idx = blockIdx.x * blockDim.x + threadIdx.x;
    if (blockIdx.y == 1) { conv_item(convsrc, convdst, idx); return; }
    int g = idx & 511;
    s16x4 a = reinterpret_cast<const s16x4*>(p0)[idx];
    s16x4 b = reinterpret_cast<const s16x4*>(p1)[idx];
    float4 bi = reinterpret_cast<const float4*>(bias)[g];
    s16x4 o;
    o.x = f2bf(sigmoidf_(bf2f(a.x) + bf2f(b.x) + bi.x));
    o.y = f2bf(sigmoidf_(bf2f(a.y) + bf2f(b.y) + bi.y));
    o.z = f2bf(sigmoidf_(bf2f(a.z) + bf2f(b.z) + bi.z));
    o.w = f2bf(sigmoidf_(bf2f(a.w) + bf2f(b.w) + bi.w));
    reinterpret_cast<s16x4*>(out_bf)[idx] = o;
}

// ---------------- combine3 (f32 sigmoid) ----------------
__global__ void combine3(
    const short* __restrict__ p0, const short* __restrict__ p1,
    const float* __restrict__ bias, float* __restrict__ out_f)
{
    int idx = blockIdx.x * blockDim.x + threadIdx.x;
    int g = idx & 511;
    s16x4 a = reinterpret_cast<const s16x4*>(p0)[idx];
    s16x4 b = reinterpret_cast<const s16x4*>(p1)[idx];
    float4 bi = reinterpret_cast<const float4*>(bias)[g];
    reinterpret_cast<float4*>(out_f)[idx] = make_float4(
        sigmoidf_(bf2f(a.x) + bf2f(b.x) + bi.x),
        sigmoidf_(bf2f(a.y) + bf2f(b.y) + bi.y),
        sigmoidf_(bf2f(a.z) + bf2f(b.z) + bi.z),
        sigmoidf_(bf2f(a.w) + bf2f(b.w) + bi.w));
}

extern "C" void kernel_launch(void* const* d_in, const int* in_sizes, int n_in,
                              void* d_out, int out_size, void* d_ws, size_t ws_size,
                              hipStream_t stream)
{
    const float* x   = (const float*)d_in[0];
    const float* W1  = (const float*)d_in[1];
    const float* b1  = (const float*)d_in[2];
    const float* W2  = (const float*)d_in[3];
    const float* b2  = (const float*)d_in[4];
    const float* W3  = (const float*)d_in[5];
    const float* b3  = (const float*)d_in[6];
    const float* wts = (const float*)d_in[7];
    const float* lst = (const float*)d_in[8];
    const float* mp  = (const float*)d_in[9];
    const float* nin = (const float*)d_in[10];
    const float* min_ = (const float*)d_in[11];
    const float* hin = (const float*)d_in[12];

    const size_t NSQ = (size_t)NN * NN;
    float* out    = (float*)d_out;          // [N,N] final MLP output
    float* out_w  = out + NSQ;              // new_weights
    float* out_n  = out + 2 * NSQ;
    float* out_m  = out + 3 * NSQ;
    float* out_h  = out + 4 * NSQ;

    // ws layout (48 MB + flags): R1 xb->w3b; R2 w1b->h1b; R3 vb; R4 w2b;
    // P = 2x8MB bf16 partials.
    short* R1 = (short*)d_ws;
    short* R2 = R1 + NSQ;
    short* R3 = R2 + NSQ;
    short* R4 = R3 + NSQ;
    short* P  = R4 + NSQ;
    int* flags = (int*)(P + 2 * NSQ);

    const int convBlocks = (int)(NSQ / 4 / 256);   // 4096 per array

    // 1: x->R1, W1->R2 (+ zero flags)
    conv2_kernel<<<dim3(convBlocks, 2), 256, 0, stream>>>(x, W1, R1, R2, flags);
    // 2: GEMM1 partials: x @ W1^T (XCD-locality 1D grid)
    gemm_partial<<<512, 512, 0, stream>>>(R1, R2, P);
    // 3: combine1 (v->R3, n/m/h, flags) + conv W2->R4
    comb1_mix<<<dim3(convBlocks, 2), 256, 0, stream>>>(
        P, P + NSQ, b1, mp, nin, min_, hin,
        R3, out_n, out_m, out_h, flags, W2, R4);
    // 4: GEMM2 partials (v @ W2^T) + STDP overlapped as blocks 512..767
    gemm_stdp<<<768, 512, 0, stream>>>(R3, R4, P, wts, lst, flags, out_w);
    // 5: combine2 (h1->R2) + conv W3->R1
    comb2_mix<<<dim3(convBlocks, 2), 256, 0, stream>>>(
        P, P + NSQ, b2, R2, W3, R1);
    // 6: GEMM3 partials: h1 @ W3^T
    gemm_partial<<<512, 512, 0, stream>>>(R2, R1, P);
    // 7: combine3: out = sigmoid(.) -> f32
    combine3<<<convBlocks, 256, 0, stream>>>(P, P + NSQ, b3, out);
}

// Round 18
// 121.324 us; speedup vs baseline: 1.2107x; 1.0131x over previous
//
#include <hip/hip_runtime.h>
#include <hip/hip_bf16.h>
#include <hip/hip_fp8.h>
#include <math.h>

// SpikingNeuralNetwork: 3 chained MFMA GEMMs + elementwise epilogues.
// N = 2048. Round 18: r17 base (122.9 us) + GEMM1 in OCP fp8 e4m3:
// x direct, W1 pre-scaled x64 (all-normal e4m3 range), partial scaled /64 in
// epilogue. Staging bytes halve (16 KB/block-iter), ds_read_b64 fragments,
// chunk-XOR swizzle q^=(r>>1)&3 (2-way banks = free). GEMM2/3 stay bf16
// (their quant error would land directly on `out`). Everything else r17.

#define NN 2048
#define BK 64
#define KHALF (NN / 2)
#define KTH (KHALF / BK)   // 16 K-tiles per half
#define NT (NN / 128)      // 16 tiles per dim

typedef __attribute__((ext_vector_type(8))) short bf16x8;
typedef __attribute__((ext_vector_type(4))) float f32x4;
typedef __attribute__((ext_vector_type(4))) short s16x4;

__device__ __forceinline__ short f2bf(float f) {
    union { float f; unsigned u; } a; a.f = f;
    unsigned r = a.u + 0x7FFFu + ((a.u >> 16) & 1u);   // RNE
    return (short)(r >> 16);
}

__device__ __forceinline__ float bf2f(short s) {
    union { unsigned u; float f; } a;
    a.u = ((unsigned)(unsigned short)s) << 16;
    return a.f;
}

__device__ __forceinline__ unsigned char f2fp8(float f) {
    __hip_fp8_e4m3 t(f);                               // OCP e4m3 on gfx950
    return t.__x;
}

__device__ __forceinline__ void gload16(const void* g, void* l) {
    __builtin_amdgcn_global_load_lds(
        (const __attribute__((address_space(1))) unsigned int*)g,
        (__attribute__((address_space(3))) unsigned int*)l, 16, 0, 0);
}

__device__ __forceinline__ float sigmoidf_(float x) {
    return 1.0f / (1.0f + expf(-x));
}

__device__ __forceinline__ void conv_item(const float* __restrict__ src,
                                          short* __restrict__ dst, int i) {
    float4 v = reinterpret_cast<const float4*>(src)[i];
    s16x4 o;
    o.x = f2bf(v.x); o.y = f2bf(v.y); o.z = f2bf(v.z); o.w = f2bf(v.w);
    reinterpret_cast<s16x4*>(dst)[i] = o;
}

__device__ __forceinline__ void conv_item_f8(const float* __restrict__ src,
                                             unsigned char* __restrict__ dst,
                                             int i, float s) {
    float4 v = reinterpret_cast<const float4*>(src)[i];
    uchar4 o = make_uchar4(f2fp8(v.x * s), f2fp8(v.y * s),
                           f2fp8(v.z * s), f2fp8(v.w * s));
    reinterpret_cast<uchar4*>(dst)[i] = o;
}

// ---------------- conv x->fp8, W1->fp8(x64) (+ zero flags) ----------------
__global__ void conv2_kernel(const float* __restrict__ s0, const float* __restrict__ s1,
                             unsigned char* __restrict__ d0,
                             unsigned char* __restrict__ d1,
                             int* __restrict__ flags)
{
    int i = blockIdx.x * blockDim.x + threadIdx.x;   // over NN*NN/4
    if (blockIdx.y == 0) {
        conv_item_f8(s0, d0, i, 1.0f);
        if (blockIdx.x < NN / 256)
            flags[blockIdx.x * blockDim.x + threadIdx.x] = 0;
    } else {
        conv_item_f8(s1, d1, i, 64.0f);
    }
}

// XCD-locality decode (r17, neutral-to-positive): bid&7 = XCD; z = xcd>>2;
// rows (xcd&3)*4 + slot&3; col = slot>>2. Bijective over 512 = 16r x 16c x 2z.
__device__ __forceinline__ void xcd_decode(int bid, int& row0, int& col0, int& z)
{
    const int xcd  = bid & 7;
    const int slot = bid >> 3;          // 0..63
    z    = xcd >> 2;
    row0 = ((xcd & 3) * 4 + (slot & 3)) * 128;
    col0 = (slot >> 2) * 128;
}

// ---------------- GEMM1: fp8 split-K=2 partial ----------------
// C_z = A[:, z*1024 +: 1024] @ B^T slice, A,B fp8 e4m3 (B pre-scaled x64).
// 128x128 tile, 8 waves (2x4) of 64x32, BK=64 (=64 B/row), dbuf LDS 32 KB.
// Chunk swizzle: LDS slot q of row r holds global chunk q ^ ((r>>1)&3)
// -> fragment ds_read_b64: 16 lanes over 8 banks x 2-way (free, m136).
__global__ __launch_bounds__(512) void gemm_f8(
    const unsigned char* __restrict__ A, const unsigned char* __restrict__ B,
    short* __restrict__ P)
{
    __shared__ unsigned char As[2][128 * BK] __attribute__((aligned(16)));  // 2x8 KB
    __shared__ unsigned char Bs[2][128 * BK] __attribute__((aligned(16)));  // 2x8 KB

    int row0, col0, z;
    xcd_decode(blockIdx.x, row0, col0, z);

    const int tid  = threadIdx.x;
    const int lane = tid & 63;
    const int wid  = tid >> 6;          // 0..7
    const int kbase = z * KHALF;        // element == byte offset
    const int wm   = (wid >> 2) * 64;
    const int wn   = (wid & 3) * 32;
    const int lrow = lane & 15;
    const int lk8  = (lane >> 4) << 3;  // 0/8/16/24

    f32x4 acc[4][2] = {};

    // one 16B chunk per thread per operand per K-tile (512 chunks/tile)
    auto stage = [&](int buf, int k0) {
        const int r = tid >> 2;                      // row 0..127
        const int q = tid & 3;                       // LDS chunk slot
        const int g = q ^ ((r >> 1) & 3);            // global chunk (inverse swz)
        gload16(A + (size_t)(row0 + r) * NN + k0 + g * 16, &As[buf][tid * 16]);
        gload16(B + (size_t)(col0 + r) * NN + k0 + g * 16, &Bs[buf][tid * 16]);
    };

    auto compute = [&](int buf) {
        long af[4][2], bfv[2][2];
#pragma unroll
        for (int i = 0; i < 4; ++i) {
            const int row = wm + i * 16 + lrow;
#pragma unroll
            for (int kk = 0; kk < 2; ++kk) {
                const int off = lk8 + kk * 32;                 // byte offset in row
                const int q   = (off >> 4) ^ ((row >> 1) & 3); // swizzled slot
                af[i][kk] = *reinterpret_cast<const long*>(
                    &As[buf][row * BK + q * 16 + (off & 15)]);
            }
        }
#pragma unroll
        for (int j = 0; j < 2; ++j) {
            const int row = wn + j * 16 + lrow;
#pragma unroll
            for (int kk = 0; kk < 2; ++kk) {
                const int off = lk8 + kk * 32;
                const int q   = (off >> 4) ^ ((row >> 1) & 3);
                bfv[j][kk] = *reinterpret_cast<const long*>(
                    &Bs[buf][row * BK + q * 16 + (off & 15)]);
            }
        }
#pragma unroll
        for (int kk = 0; kk < 2; ++kk)
#pragma unroll
            for (int i = 0; i < 4; ++i)
#pragma unroll
                for (int j = 0; j < 2; ++j)
                    acc[i][j] = __builtin_amdgcn_mfma_f32_16x16x32_fp8_fp8(
                        af[i][kk], bfv[j][kk], acc[i][j], 0, 0, 0);
    };

    stage(0, kbase);
    __syncthreads();
    int cur = 0;
    for (int t = 0; t < KTH - 1; ++t) {
        stage(cur ^ 1, kbase + (t + 1) * BK);
        compute(cur);
        __syncthreads();
        cur ^= 1;
    }
    compute(cur);

    // bf16 partial (undo W1 x64 scale) — C/D: col=lane&15, row=(lane>>4)*4+reg
    short* outp = P + (size_t)z * NN * NN;
#pragma unroll
    for (int i = 0; i < 4; ++i) {
#pragma unroll
        for (int j = 0; j < 2; ++j) {
            const int gcol = col0 + wn + j * 16 + lrow;
#pragma unroll
            for (int r = 0; r < 4; ++r) {
                const int grow = row0 + wm + i * 16 + ((lane >> 4) << 2) + r;
                outp[(size_t)grow * NN + gcol] = f2bf(acc[i][j][r] * 0.015625f);
            }
        }
    }
}

// ---------------- split-K=2 bf16 GEMM body (r7 config, GEMM2/3) ----------------
__device__ __forceinline__ void gemm_body(
    const short* __restrict__ A, const short* __restrict__ B,
    short* __restrict__ P, short (*As)[128 * BK], short (*Bs)[128 * BK],
    const int row0, const int col0, const int z)
{
    const int tid  = threadIdx.x;
    const int lane = tid & 63;
    const int wid  = tid >> 6;          // 0..7
    const int kbase = z * KHALF;
    const int wm   = (wid >> 2) * 64;
    const int wn   = (wid & 3) * 32;
    const int lrow = lane & 15;
    const int lk16 = (lane >> 4) << 3;

    f32x4 acc[4][2] = {};

    auto stage = [&](int buf, int k0) {
#pragma unroll
        for (int s = 0; s < 2; ++s) {
            int c = tid + s * 512;
            int r = c >> 3;
            int ksrc = ((c & 7) ^ (r & 7)) << 3;
            gload16(A + (size_t)(row0 + r) * NN + k0 + ksrc, &As[buf][c * 8]);
            gload16(B + (size_t)(col0 + r) * NN + k0 + ksrc, &Bs[buf][c * 8]);
        }
    };

    auto compute = [&](int buf) {
        bf16x8 af[4][2], bfv[2][2];
#pragma unroll
        for (int i = 0; i < 4; ++i) {
            const int row = wm + i * 16 + lrow;
#pragma unroll
            for (int kk = 0; kk < 2; ++kk) {
                const int ke = (lk16 + kk * 32) ^ ((row & 7) << 3);
                af[i][kk] = *reinterpret_cast<const bf16x8*>(&As[buf][row * BK + ke]);
            }
        }
#pragma unroll
        for (int j = 0; j < 2; ++j) {
            const int row = wn + j * 16 + lrow;
#pragma unroll
            for (int kk = 0; kk < 2; ++kk) {
                const int ke = (lk16 + kk * 32) ^ ((row & 7) << 3);
                bfv[j][kk] = *reinterpret_cast<const bf16x8*>(&Bs[buf][row * BK + ke]);
            }
        }
#pragma unroll
        for (int kk = 0; kk < 2; ++kk)
#pragma unroll
            for (int i = 0; i < 4; ++i)
#pragma unroll
                for (int j = 0; j < 2; ++j)
                    acc[i][j] = __builtin_amdgcn_mfma_f32_16x16x32_bf16(
                        af[i][kk], bfv[j][kk], acc[i][j], 0, 0, 0);
    };

    stage(0, kbase);
    __syncthreads();
    int cur = 0;
    for (int t = 0; t < KTH - 1; ++t) {
        stage(cur ^ 1, kbase + (t + 1) * BK);
        compute(cur);
        __syncthreads();
        cur ^= 1;
    }
    compute(cur);

    short* outp = P + (size_t)z * NN * NN;
#pragma unroll
    for (int i = 0; i < 4; ++i) {
#pragma unroll
        for (int j = 0; j < 2; ++j) {
            const int gcol = col0 + wn + j * 16 + lrow;
#pragma unroll
            for (int r = 0; r < 4; ++r) {
                const int grow = row0 + wm + i * 16 + ((lane >> 4) << 2) + r;
                outp[(size_t)grow * NN + gcol] = f2bf(acc[i][j][r]);
            }
        }
    }
}

__global__ __launch_bounds__(512) void gemm_partial(
    const short* __restrict__ A, const short* __restrict__ B,
    short* __restrict__ P)
{
    __shared__ short As[2][128 * BK] __attribute__((aligned(16)));
    __shared__ short Bs[2][128 * BK] __attribute__((aligned(16)));
    int row0, col0, z;
    xcd_decode(blockIdx.x, row0, col0, z);
    gemm_body(A, B, P, As, Bs, row0, col0, z);
}

// GEMM2 + STDP fused dispatch: 768 blocks; bid >= 512 runs STDP.
__global__ __launch_bounds__(512) void gemm_stdp(
    const short* __restrict__ A, const short* __restrict__ B,
    short* __restrict__ P,
    const float* __restrict__ w, const float* __restrict__ lst,
    const int* __restrict__ flags, float* __restrict__ outw)
{
    __shared__ short As[2][128 * BK] __attribute__((aligned(16)));
    __shared__ short Bs[2][128 * BK] __attribute__((aligned(16)));
    if (blockIdx.x >= 512) {
        const int bflat = blockIdx.x - 512;              // 0..255
#pragma unroll
        for (int u = 0; u < 8; ++u) {
            int idx = bflat * 4096 + u * 512 + threadIdx.x;  // over NN*NN/4
            int i  = idx >> 9;
            int j4 = (idx & 511) << 2;
            float4 wv = reinterpret_cast<const float4*>(w)[idx];
            float o[4] = {wv.x, wv.y, wv.z, wv.w};
            const int   rsi = flags[i];
            const float tsi = 10.0f - lst[i];
#pragma unroll
            for (int t = 0; t < 4; ++t) {
                int j = j4 + t;
                if (rsi | flags[j]) {
                    float dtm = tsi - (10.0f - lst[j]);
                    float dw = (dtm > 0.0f) ? (-0.015f * expf(-fabsf(dtm) / 25.0f))
                                            : ( 0.02f  * expf(-fabsf(dtm) / 15.0f));
                    o[t] += dw;
                }
                o[t] = fminf(1.0f, fmaxf(-1.0f, o[t]));
            }
            reinterpret_cast<float4*>(outw)[idx] = make_float4(o[0], o[1], o[2], o[3]);
        }
        return;
    }
    int row0, col0, z;
    xcd_decode(blockIdx.x, row0, col0, z);
    gemm_body(A, B, P, As, Bs, row0, col0, z);
}

// ---------------- combine1 (v/HH/spike) + merged conv(W2->bf16) ----------------
__global__ void comb1_mix(
    const short* __restrict__ p0, const short* __restrict__ p1,
    const float* __restrict__ bias,
    const float* __restrict__ mp,
    const float* __restrict__ n_in, const float* __restrict__ m_in,
    const float* __restrict__ h_in,
    short* __restrict__ out_v,
    float* __restrict__ out_n, float* __restrict__ out_m,
    float* __restrict__ out_h,
    int* __restrict__ flags,
    const float* __restrict__ convsrc, short* __restrict__ convdst)
{
    int idx = blockIdx.x * blockDim.x + threadIdx.x;   // over NN*NN/4
    if (blockIdx.y == 1) { conv_item(convsrc, convdst, idx); return; }
    int row = idx >> 9;
    int g   = idx & 511;
    s16x4 a = reinterpret_cast<const s16x4*>(p0)[idx];
    s16x4 b = reinterpret_cast<const s16x4*>(p1)[idx];
    float4 bi = reinterpret_cast<const float4*>(bias)[g];
    float pre[4] = { bf2f(a.x) + bf2f(b.x) + bi.x,
                     bf2f(a.y) + bf2f(b.y) + bi.y,
                     bf2f(a.z) + bf2f(b.z) + bi.z,
                     bf2f(a.w) + bf2f(b.w) + bi.w };
    float4 mp4 = reinterpret_cast<const float4*>(mp)[g];
    float4 n4  = reinterpret_cast<const float4*>(n_in)[g];
    float4 m4  = reinterpret_cast<const float4*>(m_in)[g];
    float4 h4  = reinterpret_cast<const float4*>(h_in)[g];
    float mpv[4] = {mp4.x, mp4.y, mp4.z, mp4.w};
    float nv[4]  = {n4.x, n4.y, n4.z, n4.w};
    float mv[4]  = {m4.x, m4.y, m4.z, m4.w};
    float hv[4]  = {h4.x, h4.y, h4.z, h4.w};
    s16x4 vb;
    float on[4], om[4], oh[4];
#pragma unroll
    for (int t = 0; t < 4; ++t) {
        float v = 0.5f * mpv[t] + sigmoidf_(pre[t]);
        if (v > 1.0f) { flags[row] = 1; v = 0.0f; }
        vb[t] = f2bf(v);
        float an = 0.01f * (v + 55.0f) / (1.0f - expf(-(v + 55.0f) / 10.0f));
        float bn = 0.125f * expf(-(v + 65.0f) / 80.0f);
        float am = 0.1f  * (v + 40.0f) / (1.0f - expf(-(v + 40.0f) / 10.0f));
        float bm = 4.0f  * expf(-(v + 65.0f) / 18.0f);
        float ah = 0.07f * expf(-(v + 65.0f) / 20.0f);
        float bh = 1.0f  / (1.0f + expf(-(v + 35.0f) / 10.0f));
        on[t] = nv[t] + 0.01f * (an * (1.0f - nv[t]) - bn * nv[t]);
        om[t] = mv[t] + 0.01f * (am * (1.0f - mv[t]) - bm * mv[t]);
        oh[t] = hv[t] + 0.01f * (ah * (1.0f - hv[t]) - bh * hv[t]);
    }
    reinterpret_cast<s16x4*>(out_v)[idx] = vb;
    reinterpret_cast<float4*>(out_n)[idx] = make_float4(on[0], on[1], on[2], on[3]);
    reinterpret_cast<float4*>(out_m)[idx] = make_float4(om[0], om[1], om[2], om[3]);
    reinterpret_cast<float4*>(out_h)[idx] = make_float4(oh[0], oh[1], oh[2], oh[3]);
}

// ---------------- combine2 (bf16 sigmoid) + merged conv(W3->bf16) ----------------
__global__ void comb2_mix(
    const short* __restrict__ p0, const short* __restrict__ p1,
    const float* __restrict__ bias,
    short* __restrict__ out_bf,
    const float* __restrict__ convsrc, short* __restrict__ convdst)
{
    int idx = blockIdx.x * blockDim.x + threadIdx.x;
    if (blockIdx.y == 1) { conv_item(convsrc, convdst, idx); return; }
    int g = idx & 511;
    s16x4 a = reinterpret_cast<const s16x4*>(p0)[idx];
    s16x4 b = reinterpret_cast<const s16x4*>(p1)[idx];
    float4 bi = reinterpret_cast<const float4*>(bias)[g];
    s16x4 o;
    o.x = f2bf(sigmoidf_(bf2f(a.x) + bf2f(b.x) + bi.x));
    o.y = f2bf(sigmoidf_(bf2f(a.y) + bf2f(b.y) + bi.y));
    o.z = f2bf(sigmoidf_(bf2f(a.z) + bf2f(b.z) + bi.z));
    o.w = f2bf(sigmoidf_(bf2f(a.w) + bf2f(b.w) + bi.w));
    reinterpret_cast<s16x4*>(out_bf)[idx] = o;
}

// ---------------- combine3 (f32 sigmoid) ----------------
__global__ void combine3(
    const short* __restrict__ p0, const short* __restrict__ p1,
    const float* __restrict__ bias, float* __restrict__ out_f)
{
    int idx = blockIdx.x * blockDim.x + threadIdx.x;
    int g = idx & 511;
    s16x4 a = reinterpret_cast<const s16x4*>(p0)[idx];
    s16x4 b = reinterpret_cast<const s16x4*>(p1)[idx];
    float4 bi = reinterpret_cast<const float4*>(bias)[g];
    reinterpret_cast<float4*>(out_f)[idx] = make_float4(
        sigmoidf_(bf2f(a.x) + bf2f(b.x) + bi.x),
        sigmoidf_(bf2f(a.y) + bf2f(b.y) + bi.y),
        sigmoidf_(bf2f(a.z) + bf2f(b.z) + bi.z),
        sigmoidf_(bf2f(a.w) + bf2f(b.w) + bi.w));
}

extern "C" void kernel_launch(void* const* d_in, const int* in_sizes, int n_in,
                              void* d_out, int out_size, void* d_ws, size_t ws_size,
                              hipStream_t stream)
{
    const float* x   = (const float*)d_in[0];
    const float* W1  = (const float*)d_in[1];
    const float* b1  = (const float*)d_in[2];
    const float* W2  = (const float*)d_in[3];
    const float* b2  = (const float*)d_in[4];
    const float* W3  = (const float*)d_in[5];
    const float* b3  = (const float*)d_in[6];
    const float* wts = (const float*)d_in[7];
    const float* lst = (const float*)d_in[8];
    const float* mp  = (const float*)d_in[9];
    const float* nin = (const float*)d_in[10];
    const float* min_ = (const float*)d_in[11];
    const float* hin = (const float*)d_in[12];

    const size_t NSQ = (size_t)NN * NN;
    float* out    = (float*)d_out;          // [N,N] final MLP output
    float* out_w  = out + NSQ;              // new_weights
    float* out_n  = out + 2 * NSQ;
    float* out_m  = out + 3 * NSQ;
    float* out_h  = out + 4 * NSQ;

    // ws layout (48 MB + flags): R1 x_fp8 -> w3b(bf16); R2 w1_fp8 -> h1b(bf16);
    // R3 vb; R4 w2b; P = 2x8MB bf16 partials.
    short* R1 = (short*)d_ws;
    short* R2 = R1 + NSQ;
    short* R3 = R2 + NSQ;
    short* R4 = R3 + NSQ;
    short* P  = R4 + NSQ;
    int* flags = (int*)(P + 2 * NSQ);

    unsigned char* R1f = (unsigned char*)R1;   // x fp8 (4 MB of the 8 MB region)
    unsigned char* R2f = (unsigned char*)R2;   // W1 fp8 (x64)

    const int convBlocks = (int)(NSQ / 4 / 256);   // 4096 per array

    // 1: x->R1f (fp8), W1->R2f (fp8 x64) (+ zero flags)
    conv2_kernel<<<dim3(convBlocks, 2), 256, 0, stream>>>(x, W1, R1f, R2f, flags);
    // 2: GEMM1 partials (fp8): x @ W1^T, scaled back /64 in epilogue
    gemm_f8<<<512, 512, 0, stream>>>(R1f, R2f, P);
    // 3: combine1 (v->R3, n/m/h, flags) + conv W2->R4 (bf16)
    comb1_mix<<<dim3(convBlocks, 2), 256, 0, stream>>>(
        P, P + NSQ, b1, mp, nin, min_, hin,
        R3, out_n, out_m, out_h, flags, W2, R4);
    // 4: GEMM2 partials (v @ W2^T, bf16) + STDP overlapped as blocks 512..767
    gemm_stdp<<<768, 512, 0, stream>>>(R3, R4, P, wts, lst, flags, out_w);
    // 5: combine2 (h1->R2) + conv W3->R1 (bf16)
    comb2_mix<<<dim3(convBlocks, 2), 256, 0, stream>>>(
        P, P + NSQ, b2, R2, W3, R1);
    // 6: GEMM3 partials: h1 @ W3^T (bf16)
    gemm_partial<<<512, 512, 0, stream>>>(R2, R1, P);
    // 7: combine3: out = sigmoid(.) -> f32
    combine3<<<convBlocks, 256, 0, stream>>>(P, P + NSQ, b3, out);
}

// Round 19
// 120.727 us; speedup vs baseline: 1.2167x; 1.0049x over previous
//
#include <hip/hip_runtime.h>
#include <hip/hip_bf16.h>
#include <hip/hip_fp8.h>
#include <math.h>

// SpikingNeuralNetwork: 3 chained MFMA GEMMs + elementwise epilogues.
// N = 2048. Round 19: r18 base (121.3 us, fp8 GEMM1) + fp8 GEMM2:
// combine1 writes v as fp8 e4m3 directly, conv-W2 -> fp8 x64, GEMM2 uses the
// shared fp8 body (epilogue /64), STDP still rides GEMM2's dispatch.
// GEMM3 stays bf16 (its quant error would land directly on `out`).

#define NN 2048
#define BK 64
#define KHALF (NN / 2)
#define KTH (KHALF / BK)   // 16 K-tiles per half
#define NT (NN / 128)      // 16 tiles per dim

typedef __attribute__((ext_vector_type(8))) short bf16x8;
typedef __attribute__((ext_vector_type(4))) float f32x4;
typedef __attribute__((ext_vector_type(4))) short s16x4;

__device__ __forceinline__ short f2bf(float f) {
    union { float f; unsigned u; } a; a.f = f;
    unsigned r = a.u + 0x7FFFu + ((a.u >> 16) & 1u);   // RNE
    return (short)(r >> 16);
}

__device__ __forceinline__ float bf2f(short s) {
    union { unsigned u; float f; } a;
    a.u = ((unsigned)(unsigned short)s) << 16;
    return a.f;
}

__device__ __forceinline__ unsigned char f2fp8(float f) {
    __hip_fp8_e4m3 t(f);                               // OCP e4m3 on gfx950
    return t.__x;
}

__device__ __forceinline__ void gload16(const void* g, void* l) {
    __builtin_amdgcn_global_load_lds(
        (const __attribute__((address_space(1))) unsigned int*)g,
        (__attribute__((address_space(3))) unsigned int*)l, 16, 0, 0);
}

__device__ __forceinline__ float sigmoidf_(float x) {
    return 1.0f / (1.0f + expf(-x));
}

__device__ __forceinline__ void conv_item(const float* __restrict__ src,
                                          short* __restrict__ dst, int i) {
    float4 v = reinterpret_cast<const float4*>(src)[i];
    s16x4 o;
    o.x = f2bf(v.x); o.y = f2bf(v.y); o.z = f2bf(v.z); o.w = f2bf(v.w);
    reinterpret_cast<s16x4*>(dst)[i] = o;
}

__device__ __forceinline__ void conv_item_f8(const float* __restrict__ src,
                                             unsigned char* __restrict__ dst,
                                             int i, float s) {
    float4 v = reinterpret_cast<const float4*>(src)[i];
    uchar4 o = make_uchar4(f2fp8(v.x * s), f2fp8(v.y * s),
                           f2fp8(v.z * s), f2fp8(v.w * s));
    reinterpret_cast<uchar4*>(dst)[i] = o;
}

// ---------------- conv x->fp8, W1->fp8(x64) (+ zero flags) ----------------
__global__ void conv2_kernel(const float* __restrict__ s0, const float* __restrict__ s1,
                             unsigned char* __restrict__ d0,
                             unsigned char* __restrict__ d1,
                             int* __restrict__ flags)
{
    int i = blockIdx.x * blockDim.x + threadIdx.x;   // over NN*NN/4
    if (blockIdx.y == 0) {
        conv_item_f8(s0, d0, i, 1.0f);
        if (blockIdx.x < NN / 256)
            flags[blockIdx.x * blockDim.x + threadIdx.x] = 0;
    } else {
        conv_item_f8(s1, d1, i, 64.0f);
    }
}

// XCD-locality decode: bid&7 = XCD; z = xcd>>2; rows (xcd&3)*4 + slot&3;
// col = slot>>2. Bijective over 512 = 16r x 16c x 2z.
__device__ __forceinline__ void xcd_decode(int bid, int& row0, int& col0, int& z)
{
    const int xcd  = bid & 7;
    const int slot = bid >> 3;          // 0..63
    z    = xcd >> 2;
    row0 = ((xcd & 3) * 4 + (slot & 3)) * 128;
    col0 = (slot >> 2) * 128;
}

// ---------------- fp8 split-K=2 GEMM body ----------------
// C_z = A[:, z*1024 +: 1024] @ B^T slice, A,B fp8 e4m3; epilogue scales by
// `esc` (undoes operand pre-scale). 128x128 tile, 8 waves (2x4), BK=64
// (=64 B/row), dbuf LDS 32 KB. Chunk swizzle q ^= (r>>1)&3 (2-way = free).
__device__ __forceinline__ void gemm_f8_body(
    const unsigned char* __restrict__ A, const unsigned char* __restrict__ B,
    short* __restrict__ P,
    unsigned char (*As)[128 * BK], unsigned char (*Bs)[128 * BK],
    const int row0, const int col0, const int z, const float esc)
{
    const int tid  = threadIdx.x;
    const int lane = tid & 63;
    const int wid  = tid >> 6;          // 0..7
    const int kbase = z * KHALF;        // element == byte offset
    const int wm   = (wid >> 2) * 64;
    const int wn   = (wid & 3) * 32;
    const int lrow = lane & 15;
    const int lk8  = (lane >> 4) << 3;  // 0/8/16/24

    f32x4 acc[4][2] = {};

    auto stage = [&](int buf, int k0) {
        const int r = tid >> 2;                      // row 0..127
        const int q = tid & 3;                       // LDS chunk slot
        const int g = q ^ ((r >> 1) & 3);            // global chunk (inverse swz)
        gload16(A + (size_t)(row0 + r) * NN + k0 + g * 16, &As[buf][tid * 16]);
        gload16(B + (size_t)(col0 + r) * NN + k0 + g * 16, &Bs[buf][tid * 16]);
    };

    auto compute = [&](int buf) {
        long af[4][2], bfv[2][2];
#pragma unroll
        for (int i = 0; i < 4; ++i) {
            const int row = wm + i * 16 + lrow;
#pragma unroll
            for (int kk = 0; kk < 2; ++kk) {
                const int off = lk8 + kk * 32;                 // byte offset in row
                const int q   = (off >> 4) ^ ((row >> 1) & 3); // swizzled slot
                af[i][kk] = *reinterpret_cast<const long*>(
                    &As[buf][row * BK + q * 16 + (off & 15)]);
            }
        }
#pragma unroll
        for (int j = 0; j < 2; ++j) {
            const int row = wn + j * 16 + lrow;
#pragma unroll
            for (int kk = 0; kk < 2; ++kk) {
                const int off = lk8 + kk * 32;
                const int q   = (off >> 4) ^ ((row >> 1) & 3);
                bfv[j][kk] = *reinterpret_cast<const long*>(
                    &Bs[buf][row * BK + q * 16 + (off & 15)]);
            }
        }
#pragma unroll
        for (int kk = 0; kk < 2; ++kk)
#pragma unroll
            for (int i = 0; i < 4; ++i)
#pragma unroll
                for (int j = 0; j < 2; ++j)
                    acc[i][j] = __builtin_amdgcn_mfma_f32_16x16x32_fp8_fp8(
                        af[i][kk], bfv[j][kk], acc[i][j], 0, 0, 0);
    };

    stage(0, kbase);
    __syncthreads();
    int cur = 0;
    for (int t = 0; t < KTH - 1; ++t) {
        stage(cur ^ 1, kbase + (t + 1) * BK);
        compute(cur);
        __syncthreads();
        cur ^= 1;
    }
    compute(cur);

    // bf16 partial (x esc) — C/D: col=lane&15, row=(lane>>4)*4+reg
    short* outp = P + (size_t)z * NN * NN;
#pragma unroll
    for (int i = 0; i < 4; ++i) {
#pragma unroll
        for (int j = 0; j < 2; ++j) {
            const int gcol = col0 + wn + j * 16 + lrow;
#pragma unroll
            for (int r = 0; r < 4; ++r) {
                const int grow = row0 + wm + i * 16 + ((lane >> 4) << 2) + r;
                outp[(size_t)grow * NN + gcol] = f2bf(acc[i][j][r] * esc);
            }
        }
    }
}

__global__ __launch_bounds__(512) void gemm_f8(
    const unsigned char* __restrict__ A, const unsigned char* __restrict__ B,
    short* __restrict__ P)
{
    __shared__ unsigned char As[2][128 * BK] __attribute__((aligned(16)));
    __shared__ unsigned char Bs[2][128 * BK] __attribute__((aligned(16)));
    int row0, col0, z;
    xcd_decode(blockIdx.x, row0, col0, z);
    gemm_f8_body(A, B, P, As, Bs, row0, col0, z, 0.015625f);
}

// GEMM2 (fp8) + STDP fused dispatch: 768 blocks; bid >= 512 runs STDP.
__global__ __launch_bounds__(512) void gemm_f8_stdp(
    const unsigned char* __restrict__ A, const unsigned char* __restrict__ B,
    short* __restrict__ P,
    const float* __restrict__ w, const float* __restrict__ lst,
    const int* __restrict__ flags, float* __restrict__ outw)
{
    __shared__ unsigned char As[2][128 * BK] __attribute__((aligned(16)));
    __shared__ unsigned char Bs[2][128 * BK] __attribute__((aligned(16)));
    if (blockIdx.x >= 512) {
        const int bflat = blockIdx.x - 512;              // 0..255
#pragma unroll
        for (int u = 0; u < 8; ++u) {
            int idx = bflat * 4096 + u * 512 + threadIdx.x;  // over NN*NN/4
            int i  = idx >> 9;
            int j4 = (idx & 511) << 2;
            float4 wv = reinterpret_cast<const float4*>(w)[idx];
            float o[4] = {wv.x, wv.y, wv.z, wv.w};
            const int   rsi = flags[i];
            const float tsi = 10.0f - lst[i];
#pragma unroll
            for (int t = 0; t < 4; ++t) {
                int j = j4 + t;
                if (rsi | flags[j]) {
                    float dtm = tsi - (10.0f - lst[j]);
                    float dw = (dtm > 0.0f) ? (-0.015f * expf(-fabsf(dtm) / 25.0f))
                                            : ( 0.02f  * expf(-fabsf(dtm) / 15.0f));
                    o[t] += dw;
                }
                o[t] = fminf(1.0f, fmaxf(-1.0f, o[t]));
            }
            reinterpret_cast<float4*>(outw)[idx] = make_float4(o[0], o[1], o[2], o[3]);
        }
        return;
    }
    int row0, col0, z;
    xcd_decode(blockIdx.x, row0, col0, z);
    gemm_f8_body(A, B, P, As, Bs, row0, col0, z, 0.015625f);
}

// ---------------- split-K=2 bf16 GEMM (GEMM3) ----------------
__global__ __launch_bounds__(512) void gemm_partial(
    const short* __restrict__ A, const short* __restrict__ B,
    short* __restrict__ P)
{
    __shared__ short As[2][128 * BK] __attribute__((aligned(16)));
    __shared__ short Bs[2][128 * BK] __attribute__((aligned(16)));

    int row0, col0, z;
    xcd_decode(blockIdx.x, row0, col0, z);

    const int tid  = threadIdx.x;
    const int lane = tid & 63;
    const int wid  = tid >> 6;          // 0..7
    const int kbase = z * KHALF;
    const int wm   = (wid >> 2) * 64;
    const int wn   = (wid & 3) * 32;
    const int lrow = lane & 15;
    const int lk16 = (lane >> 4) << 3;

    f32x4 acc[4][2] = {};

    auto stage = [&](int buf, int k0) {
#pragma unroll
        for (int s = 0; s < 2; ++s) {
            int c = tid + s * 512;
            int r = c >> 3;
            int ksrc = ((c & 7) ^ (r & 7)) << 3;
            gload16(A + (size_t)(row0 + r) * NN + k0 + ksrc, &As[buf][c * 8]);
            gload16(B + (size_t)(col0 + r) * NN + k0 + ksrc, &Bs[buf][c * 8]);
        }
    };

    auto compute = [&](int buf) {
        bf16x8 af[4][2], bfv[2][2];
#pragma unroll
        for (int i = 0; i < 4; ++i) {
            const int row = wm + i * 16 + lrow;
#pragma unroll
            for (int kk = 0; kk < 2; ++kk) {
                const int ke = (lk16 + kk * 32) ^ ((row & 7) << 3);
                af[i][kk] = *reinterpret_cast<const bf16x8*>(&As[buf][row * BK + ke]);
            }
        }
#pragma unroll
        for (int j = 0; j < 2; ++j) {
            const int row = wn + j * 16 + lrow;
#pragma unroll
            for (int kk = 0; kk < 2; ++kk) {
                const int ke = (lk16 + kk * 32) ^ ((row & 7) << 3);
                bfv[j][kk] = *reinterpret_cast<const bf16x8*>(&Bs[buf][row * BK + ke]);
            }
        }
#pragma unroll
        for (int kk = 0; kk < 2; ++kk)
#pragma unroll
            for (int i = 0; i < 4; ++i)
#pragma unroll
                for (int j = 0; j < 2; ++j)
                    acc[i][j] = __builtin_amdgcn_mfma_f32_16x16x32_bf16(
                        af[i][kk], bfv[j][kk], acc[i][j], 0, 0, 0);
    };

    stage(0, kbase);
    __syncthreads();
    int cur = 0;
    for (int t = 0; t < KTH - 1; ++t) {
        stage(cur ^ 1, kbase + (t + 1) * BK);
        compute(cur);
        __syncthreads();
        cur ^= 1;
    }
    compute(cur);

    short* outp = P + (size_t)z * NN * NN;
#pragma unroll
    for (int i = 0; i < 4; ++i) {
#pragma unroll
        for (int j = 0; j < 2; ++j) {
            const int gcol = col0 + wn + j * 16 + lrow;
#pragma unroll
            for (int r = 0; r < 4; ++r) {
                const int grow = row0 + wm + i * 16 + ((lane >> 4) << 2) + r;
                outp[(size_t)grow * NN + gcol] = f2bf(acc[i][j][r]);
            }
        }
    }
}

// ------- combine1 (v/HH/spike; v -> fp8) + merged conv(W2 -> fp8 x64) -------
__global__ void comb1_mix(
    const short* __restrict__ p0, const short* __restrict__ p1,
    const float* __restrict__ bias,
    const float* __restrict__ mp,
    const float* __restrict__ n_in, const float* __restrict__ m_in,
    const float* __restrict__ h_in,
    unsigned char* __restrict__ out_v,
    float* __restrict__ out_n, float* __restrict__ out_m,
    float* __restrict__ out_h,
    int* __restrict__ flags,
    const float* __restrict__ convsrc, unsigned char* __restrict__ convdst)
{
    int idx = blockIdx.x * blockDim.x + threadIdx.x;   // over NN*NN/4
    if (blockIdx.y == 1) { conv_item_f8(convsrc, convdst, idx, 64.0f); return; }
    int row = idx >> 9;
    int g   = idx & 511;
    s16x4 a = reinterpret_cast<const s16x4*>(p0)[idx];
    s16x4 b = reinterpret_cast<const s16x4*>(p1)[idx];
    float4 bi = reinterpret_cast<const float4*>(bias)[g];
    float pre[4] = { bf2f(a.x) + bf2f(b.x) + bi.x,
                     bf2f(a.y) + bf2f(b.y) + bi.y,
                     bf2f(a.z) + bf2f(b.z) + bi.z,
                     bf2f(a.w) + bf2f(b.w) + bi.w };
    float4 mp4 = reinterpret_cast<const float4*>(mp)[g];
    float4 n4  = reinterpret_cast<const float4*>(n_in)[g];
    float4 m4  = reinterpret_cast<const float4*>(m_in)[g];
    float4 h4  = reinterpret_cast<const float4*>(h_in)[g];
    float mpv[4] = {mp4.x, mp4.y, mp4.z, mp4.w};
    float nv[4]  = {n4.x, n4.y, n4.z, n4.w};
    float mv[4]  = {m4.x, m4.y, m4.z, m4.w};
    float hv[4]  = {h4.x, h4.y, h4.z, h4.w};
    uchar4 vb;
    float on[4], om[4], oh[4];
    float vq[4];
#pragma unroll
    for (int t = 0; t < 4; ++t) {
        float v = 0.5f * mpv[t] + sigmoidf_(pre[t]);
        if (v > 1.0f) { flags[row] = 1; v = 0.0f; }
        vq[t] = v;
        float an = 0.01f * (v + 55.0f) / (1.0f - expf(-(v + 55.0f) / 10.0f));
        float bn = 0.125f * expf(-(v + 65.0f) / 80.0f);
        float am = 0.1f  * (v + 40.0f) / (1.0f - expf(-(v + 40.0f) / 10.0f));
        float bm = 4.0f  * expf(-(v + 65.0f) / 18.0f);
        float ah = 0.07f * expf(-(v + 65.0f) / 20.0f);
        float bh = 1.0f  / (1.0f + expf(-(v + 35.0f) / 10.0f));
        on[t] = nv[t] + 0.01f * (an * (1.0f - nv[t]) - bn * nv[t]);
        om[t] = mv[t] + 0.01f * (am * (1.0f - mv[t]) - bm * mv[t]);
        oh[t] = hv[t] + 0.01f * (ah * (1.0f - hv[t]) - bh * hv[t]);
    }
    vb = make_uchar4(f2fp8(vq[0]), f2fp8(vq[1]), f2fp8(vq[2]), f2fp8(vq[3]));
    reinterpret_cast<uchar4*>(out_v)[idx] = vb;
    reinterpret_cast<float4*>(out_n)[idx] = make_float4(on[0], on[1], on[2], on[3]);
    reinterpret_cast<float4*>(out_m)[idx] = make_float4(om[0], om[1], om[2], om[3]);
    reinterpret_cast<float4*>(out_h)[idx] = make_float4(oh[0], oh[1], oh[2], oh[3]);
}

// ---------------- combine2 (bf16 sigmoid) + merged conv(W3->bf16) ----------------
__global__ void comb2_mix(
    const short* __restrict__ p0, const short* __restrict__ p1,
    const float* __restrict__ bias,
    short* __restrict__ out_bf,
    const float* __restrict__ convsrc, short* __restrict__ convdst)
{
    int idx = blockIdx.x * blockDim.x + threadIdx.x;
    if (blockIdx.y == 1) { conv_item(convsrc, convdst, idx); return; }
    int g = idx & 511;
    s16x4 a = reinterpret_cast<const s16x4*>(p0)[idx];
    s16x4 b = reinterpret_cast<const s16x4*>(p1)[idx];
    float4 bi = reinterpret_cast<const float4*>(bias)[g];
    s16x4 o;
    o.x = f2bf(sigmoidf_(bf2f(a.x) + bf2f(b.x) + bi.x));
    o.y = f2bf(sigmoidf_(bf2f(a.y) + bf2f(b.y) + bi.y));
    o.z = f2bf(sigmoidf_(bf2f(a.z) + bf2f(b.z) + bi.z));
    o.w = f2bf(sigmoidf_(bf2f(a.w) + bf2f(b.w) + bi.w));
    reinterpret_cast<s16x4*>(out_bf)[idx] = o;
}

// ---------------- combine3 (f32 sigmoid) ----------------
__global__ void combine3(
    const short* __restrict__ p0, const short* __restrict__ p1,
    const float* __restrict__ bias, float* __restrict__ out_f)
{
    int idx = blockIdx.x * blockDim.x + threadIdx.x;
    int g = idx & 511;
    s16x4 a = reinterpret_cast<const s16x4*>(p0)[idx];
    s16x4 b = reinterpret_cast<const s16x4*>(p1)[idx];
    float4 bi = reinterpret_cast<const float4*>(bias)[g];
    reinterpret_cast<float4*>(out_f)[idx] = make_float4(
        sigmoidf_(bf2f(a.x) + bf2f(b.x) + bi.x),
        sigmoidf_(bf2f(a.y) + bf2f(b.y) + bi.y),
        sigmoidf_(bf2f(a.z) + bf2f(b.z) + bi.z),
        sigmoidf_(bf2f(a.w) + bf2f(b.w) + bi.w));
}

extern "C" void kernel_launch(void* const* d_in, const int* in_sizes, int n_in,
                              void* d_out, int out_size, void* d_ws, size_t ws_size,
                              hipStream_t stream)
{
    const float* x   = (const float*)d_in[0];
    const float* W1  = (const float*)d_in[1];
    const float* b1  = (const float*)d_in[2];
    const float* W2  = (const float*)d_in[3];
    const float* b2  = (const float*)d_in[4];
    const float* W3  = (const float*)d_in[5];
    const float* b3  = (const float*)d_in[6];
    const float* wts = (const float*)d_in[7];
    const float* lst = (const float*)d_in[8];
    const float* mp  = (const float*)d_in[9];
    const float* nin = (const float*)d_in[10];
    const float* min_ = (const float*)d_in[11];
    const float* hin = (const float*)d_in[12];

    const size_t NSQ = (size_t)NN * NN;
    float* out    = (float*)d_out;          // [N,N] final MLP output
    float* out_w  = out + NSQ;              // new_weights
    float* out_n  = out + 2 * NSQ;
    float* out_m  = out + 3 * NSQ;
    float* out_h  = out + 4 * NSQ;

    // ws layout (48 MB + flags): R1 x_fp8 -> w3b(bf16); R2 w1_fp8 -> h1b(bf16);
    // R3 v_fp8; R4 w2_fp8; P = 2x8MB bf16 partials.
    short* R1 = (short*)d_ws;
    short* R2 = R1 + NSQ;
    short* R3 = R2 + NSQ;
    short* R4 = R3 + NSQ;
    short* P  = R4 + NSQ;
    int* flags = (int*)(P + 2 * NSQ);

    unsigned char* R1f = (unsigned char*)R1;   // x fp8
    unsigned char* R2f = (unsigned char*)R2;   // W1 fp8 (x64)
    unsigned char* R3f = (unsigned char*)R3;   // v fp8
    unsigned char* R4f = (unsigned char*)R4;   // W2 fp8 (x64)

    const int convBlocks = (int)(NSQ / 4 / 256);   // 4096 per array

    // 1: x->R1f (fp8), W1->R2f (fp8 x64) (+ zero flags)
    conv2_kernel<<<dim3(convBlocks, 2), 256, 0, stream>>>(x, W1, R1f, R2f, flags);
    // 2: GEMM1 partials (fp8): x @ W1^T, /64 in epilogue
    gemm_f8<<<512, 512, 0, stream>>>(R1f, R2f, P);
    // 3: combine1 (v->R3f fp8, n/m/h, flags) + conv W2->R4f (fp8 x64)
    comb1_mix<<<dim3(convBlocks, 2), 256, 0, stream>>>(
        P, P + NSQ, b1, mp, nin, min_, hin,
        R3f, out_n, out_m, out_h, flags, W2, R4f);
    // 4: GEMM2 partials (fp8: v @ W2^T, /64) + STDP as blocks 512..767
    gemm_f8_stdp<<<768, 512, 0, stream>>>(R3f, R4f, P, wts, lst, flags, out_w);
    // 5: combine2 (h1->R2 bf16) + conv W3->R1 (bf16)
    comb2_mix<<<dim3(convBlocks, 2), 256, 0, stream>>>(
        P, P + NSQ, b2, R2, W3, R1);
    // 6: GEMM3 partials: h1 @ W3^T (bf16)
    gemm_partial<<<512, 512, 0, stream>>>(R2, R1, P);
    // 7: combine3: out = sigmoid(.) -> f32
    combine3<<<convBlocks, 256, 0, stream>>>(P, P + NSQ, b3, out);
}